// Round 1
// baseline (667.900 us; speedup 1.0000x reference)
//
#include <hip/hip_runtime.h>
#include <hip/hip_bf16.h>
#include <stdint.h>
#include <stddef.h>

// Problem constants
#define T_SEQ 2048
#define DM    4096
#define NQH   32
#define NKVH  8
#define HD    128
#define ATTN_MULT 0.08838834764831845f

typedef __attribute__((ext_vector_type(8))) short bf16x8;
typedef __attribute__((ext_vector_type(4))) float f32x4;
typedef __attribute__((ext_vector_type(4))) unsigned int u32x4;

__device__ __forceinline__ unsigned short f2b(float f) {
  unsigned u = __builtin_bit_cast(unsigned, f);
  u = u + 0x7FFFu + ((u >> 16) & 1u);
  return (unsigned short)(u >> 16);
}
__device__ __forceinline__ float b2f(unsigned short h) {
  unsigned u = ((unsigned)h) << 16;
  return __builtin_bit_cast(float, u);
}

typedef const __attribute__((address_space(1))) void* gptr1_t;
typedef __attribute__((address_space(3))) void* lptr3_t;
__device__ __forceinline__ void gl_lds16(const void* g, void* l) {
  __builtin_amdgcn_global_load_lds((gptr1_t)g, (lptr3_t)l, 16, 0, 0);
}

// ---------------------------------------------------------------------------
// Transpose + cast: W (K,N) f32 -> WT (N,K) bf16
// ---------------------------------------------------------------------------
__global__ __launch_bounds__(256) void transpose_cast_kernel(
    const float* __restrict__ W, unsigned short* __restrict__ WT, int K, int N) {
  __shared__ float tile[64][65];
  int k0 = blockIdx.x * 64;
  int n0 = blockIdx.y * 64;
  int t = threadIdx.x;
  int rr = t >> 4;   // 0..15
  int cc = t & 15;   // float4 column
#pragma unroll
  for (int c = 0; c < 4; ++c) {
    int row = c * 16 + rr;
    float4 v = *(const float4*)&W[(size_t)(k0 + row) * N + n0 + cc * 4];
    tile[row][cc * 4 + 0] = v.x;
    tile[row][cc * 4 + 1] = v.y;
    tile[row][cc * 4 + 2] = v.z;
    tile[row][cc * 4 + 3] = v.w;
  }
  __syncthreads();
  int orow = t >> 2;         // 0..63 (output row = original col)
  int kb = (t & 3) * 16;     // 16 k-values
  u32x4 o1, o2;
#pragma unroll
  for (int u = 0; u < 4; ++u) {
    o1[u] = (unsigned)f2b(tile[kb + 2 * u][orow]) |
            ((unsigned)f2b(tile[kb + 2 * u + 1][orow]) << 16);
    o2[u] = (unsigned)f2b(tile[kb + 8 + 2 * u][orow]) |
            ((unsigned)f2b(tile[kb + 9 + 2 * u][orow]) << 16);
  }
  unsigned short* dst = &WT[(size_t)(n0 + orow) * K + k0 + kb];
  *(u32x4*)dst = o1;
  *(u32x4*)(dst + 8) = o2;
}

// ---------------------------------------------------------------------------
// Cast 3 activation tensors f32 -> bf16 (each T_SEQ*DM elements)
// ---------------------------------------------------------------------------
__global__ __launch_bounds__(256) void cast3_kernel(
    const float* __restrict__ a0, const float* __restrict__ a1, const float* __restrict__ a2,
    unsigned short* __restrict__ b0, unsigned short* __restrict__ b1, unsigned short* __restrict__ b2) {
  const float* in = blockIdx.z == 0 ? a0 : (blockIdx.z == 1 ? a1 : a2);
  unsigned short* out = blockIdx.z == 0 ? b0 : (blockIdx.z == 1 ? b1 : b2);
  size_t idx = ((size_t)blockIdx.x * 256 + threadIdx.x) * 8;
  float4 x = *(const float4*)(in + idx);
  float4 y = *(const float4*)(in + idx + 4);
  u32x4 v;
  v[0] = (unsigned)f2b(x.x) | ((unsigned)f2b(x.y) << 16);
  v[1] = (unsigned)f2b(x.z) | ((unsigned)f2b(x.w) << 16);
  v[2] = (unsigned)f2b(y.x) | ((unsigned)f2b(y.y) << 16);
  v[3] = (unsigned)f2b(y.z) | ((unsigned)f2b(y.w) << 16);
  *(u32x4*)(out + idx) = v;
}

// ---------------------------------------------------------------------------
// GEMM: C(M,N) = A(M,K) * BT(N,K)^T   bf16 inputs, fp32 accum
// m97 structure: 128x128 tile, BK=32, global_load_lds(16B), 16x16x32 MFMA
// DUAL: blockIdx.z selects (A0,B0,C0)/(A1,B1,C1)
// ---------------------------------------------------------------------------
template <bool F32OUT, bool DUAL>
__global__ __launch_bounds__(256) void gemm_bt_kernel(
    const unsigned short* __restrict__ A0, const unsigned short* __restrict__ B0, void* __restrict__ C0,
    const unsigned short* __restrict__ A1, const unsigned short* __restrict__ B1, void* __restrict__ C1,
    int M, int N, int K) {
  __shared__ unsigned short As[128 * 32];
  __shared__ unsigned short Bs[128 * 32];
  const unsigned short* A = A0;
  const unsigned short* BT = B0;
  void* C = C0;
  if (DUAL && blockIdx.z == 1) { A = A1; BT = B1; C = C1; }

  int m0 = blockIdx.y * 128;
  int n0 = blockIdx.x * 128;
  int t = threadIdx.x;
  int w = t >> 6, l = t & 63;
  int wr = w >> 1, wc = w & 1;
  int lr = l & 15, lh = l >> 4;

  f32x4 acc[4][4] = {};

  // staging: chunk = w*2+c (0..7), each 1KB; row = chunk*16 + (l>>2), col = (l&3)*8
  int srow0 = (w * 2 + 0) * 16 + (l >> 2);
  int srow1 = (w * 2 + 1) * 16 + (l >> 2);
  int scol = (l & 3) * 8;
  const unsigned short* Aa0 = A + (size_t)(m0 + srow0) * K + scol;
  const unsigned short* Aa1 = A + (size_t)(m0 + srow1) * K + scol;
  const unsigned short* Ba0 = BT + (size_t)(n0 + srow0) * K + scol;
  const unsigned short* Ba1 = BT + (size_t)(n0 + srow1) * K + scol;
  unsigned short* Al0 = &As[(w * 2 + 0) * 512];
  unsigned short* Al1 = &As[(w * 2 + 1) * 512];
  unsigned short* Bl0 = &Bs[(w * 2 + 0) * 512];
  unsigned short* Bl1 = &Bs[(w * 2 + 1) * 512];

  for (int k0 = 0; k0 < K; k0 += 32) {
    gl_lds16(Aa0 + k0, Al0);
    gl_lds16(Aa1 + k0, Al1);
    gl_lds16(Ba0 + k0, Bl0);
    gl_lds16(Ba1 + k0, Bl1);
    __syncthreads();
    bf16x8 af[4], bfr[4];
#pragma unroll
    for (int i = 0; i < 4; ++i)
      af[i] = *(const bf16x8*)&As[(wr * 64 + i * 16 + lr) * 32 + lh * 8];
#pragma unroll
    for (int j = 0; j < 4; ++j)
      bfr[j] = *(const bf16x8*)&Bs[(wc * 64 + j * 16 + lr) * 32 + lh * 8];
#pragma unroll
    for (int i = 0; i < 4; ++i)
#pragma unroll
      for (int j = 0; j < 4; ++j)
        acc[i][j] = __builtin_amdgcn_mfma_f32_16x16x32_bf16(af[i], bfr[j], acc[i][j], 0, 0, 0);
    __syncthreads();
  }

#pragma unroll
  for (int i = 0; i < 4; ++i) {
#pragma unroll
    for (int j = 0; j < 4; ++j) {
#pragma unroll
      for (int r = 0; r < 4; ++r) {
        int row = m0 + wr * 64 + i * 16 + lh * 4 + r;
        int col = n0 + wc * 64 + j * 16 + lr;
        if constexpr (F32OUT)
          ((float*)C)[(size_t)row * N + col] = acc[i][j][r];
        else
          ((unsigned short*)C)[(size_t)row * N + col] = f2b(acc[i][j][r]);
      }
    }
  }
}

// ---------------------------------------------------------------------------
// RoPE in place on (T, nheads*128) bf16. One thread per (t, h, i) pair, i<64.
// out[i] = x[i]*cos - x[i+64]*sin ; out[i+64] = x[i+64]*cos + x[i]*sin
// ---------------------------------------------------------------------------
__global__ __launch_bounds__(256) void rope_kernel(unsigned short* __restrict__ X, int hshift) {
  int nheads = 1 << hshift;
  int idx = blockIdx.x * 256 + threadIdx.x;
  int i = idx & 63;
  int rest = idx >> 6;
  int hh = rest & (nheads - 1);
  int tpos = rest >> hshift;
  // inv_freq = 10000^{-i/64} = exp2(-i * log2(10000)/64)
  float invf = exp2f(-(float)i * (13.287712379549449f / 64.0f));
  float phase = (float)tpos * invf;
  float s, c;
  sincosf(phase, &s, &c);
  size_t base = (size_t)tpos * ((size_t)nheads * HD) + (size_t)hh * HD + i;
  float x1 = b2f(X[base]);
  float x2 = b2f(X[base + 64]);
  X[base] = f2b(x1 * c - x2 * s);
  X[base + 64] = f2b(x2 * c + x1 * s);
}

// ---------------------------------------------------------------------------
// V (T, NKVH*HD) bf16 -> VT (NKVH, HD, T) bf16
// ---------------------------------------------------------------------------
__global__ __launch_bounds__(256) void vtrans_kernel(
    const unsigned short* __restrict__ V, unsigned short* __restrict__ VT) {
  size_t flat = ((size_t)blockIdx.x * 256 + threadIdx.x) * 8;
  int t8 = (int)(flat & (T_SEQ - 1));
  int dh = (int)(flat >> 11);  // kvh*HD + d
  u32x4 v;
#pragma unroll
  for (int u = 0; u < 4; ++u) {
    unsigned short lo = V[(size_t)(t8 + 2 * u) * (NKVH * HD) + dh];
    unsigned short hi = V[(size_t)(t8 + 2 * u + 1) * (NKVH * HD) + dh];
    v[u] = (unsigned)lo | ((unsigned)hi << 16);
  }
  *(u32x4*)(VT + flat) = v;
}

// ---------------------------------------------------------------------------
// Flash attention, GQA 32 q-heads / 8 kv-heads, causal, tanh soft-cap 30.
// Block: 4 waves x 16 q-rows = 64 q-rows. KV tiles of 64.
// K tile LDS [64][128], VT tile LDS [128][64], both XOR-swizzled
// (linear global_load_lds dest + pre-swizzled global source, rule #21).
// ---------------------------------------------------------------------------
__global__ __launch_bounds__(256) void attn_kernel(
    const unsigned short* __restrict__ Q,   // (T, NQH*HD) roped
    const unsigned short* __restrict__ Kx,  // (T, NKVH*HD) roped
    const unsigned short* __restrict__ VT,  // (NKVH, HD, T)
    unsigned short* __restrict__ O) {       // (T, NQH*HD)
  __shared__ unsigned short Ks[64 * 128];
  __shared__ unsigned short Vs[128 * 64];
  __shared__ unsigned short Ps[4][16 * 64];

  int qt = blockIdx.x;
  int h = blockIdx.y;
  int kvh = h >> 2;
  int t = threadIdx.x;
  int w = t >> 6, l = t & 63;
  int lr = l & 15, lh = l >> 4;

  // Q fragments (held in registers for the whole block)
  bf16x8 qf[4];
  int qrow = qt * 64 + w * 16 + lr;
  const unsigned short* qp = Q + (size_t)qrow * (NQH * HD) + h * HD + lh * 8;
#pragma unroll
  for (int kk = 0; kk < 4; ++kk) qf[kk] = *(const bf16x8*)(qp + kk * 32);

  f32x4 oacc[8] = {};
  float mrow[4] = {-1e30f, -1e30f, -1e30f, -1e30f};
  float lrow[4] = {0.f, 0.f, 0.f, 0.f};

  const char* KgB = (const char*)Kx + (size_t)kvh * HD * 2;          // + t*2048 + colbyte
  const char* VgB = (const char*)VT + (size_t)kvh * HD * T_SEQ * 2;  // + d*4096 + t*2

  unsigned short* pw = Ps[w];

  for (int kt = 0; kt <= qt; ++kt) {
    __syncthreads();
    // ---- stage K tile (16KB) and VT tile (16KB)
#pragma unroll
    for (int c = 0; c < 4; ++c) {
      int chunk = w * 4 + c;
      int p = chunk * 1024 + l * 16;
      {
        int row = p >> 8;                 // key within tile
        int cb = p & 255;                 // linear LDS colbyte
        int cbl = cb ^ ((row & 7) << 4);  // pre-swizzled global source
        gl_lds16(KgB + (size_t)(kt * 64 + row) * (NKVH * HD * 2) + cbl,
                 (char*)Ks + chunk * 1024);
      }
      {
        int row = p >> 7;  // d
        int cb = p & 127;
        int cbl = cb ^ ((row & 7) << 4);
        gl_lds16(VgB + (size_t)row * (T_SEQ * 2) + (size_t)kt * 128 + cbl,
                 (char*)Vs + chunk * 1024);
      }
    }
    __syncthreads();

    // ---- S = Q K^T  (4 column tiles of 16 keys)
    f32x4 sa[4];
#pragma unroll
    for (int ct = 0; ct < 4; ++ct) {
      f32x4 z = {};
#pragma unroll
      for (int kk = 0; kk < 4; ++kk) {
        int row = ct * 16 + lr;
        int cb = (kk * 32 + lh * 8) * 2;
        bf16x8 kf = *(const bf16x8*)((const char*)Ks + row * 256 + (cb ^ ((row & 7) << 4)));
        z = __builtin_amdgcn_mfma_f32_16x16x32_bf16(qf[kk], kf, z, 0, 0, 0);
      }
      sa[ct] = z;
    }

    // ---- soft-cap + mask + online softmax
    float pv[4][4];
    float mx[4];
#pragma unroll
    for (int i = 0; i < 4; ++i) {
      int qg = qt * 64 + w * 16 + lh * 4 + i;
      float mi = -1e30f;
#pragma unroll
      for (int ct = 0; ct < 4; ++ct) {
        int kg = kt * 64 + ct * 16 + lr;
        float x = sa[ct][i] * ATTN_MULT;
        // 30*tanh(x/30) = 30 - 60/(exp(x/15)+1)
        x = 30.0f - 60.0f / (__expf(x * (1.0f / 15.0f)) + 1.0f);
        if (kg > qg) x = -1e30f;
        pv[ct][i] = x;
        mi = fmaxf(mi, x);
      }
      mx[i] = mi;
    }
#pragma unroll
    for (int off = 1; off < 16; off <<= 1)
#pragma unroll
      for (int i = 0; i < 4; ++i) mx[i] = fmaxf(mx[i], __shfl_xor(mx[i], off, 64));

    float scal[4];
#pragma unroll
    for (int i = 0; i < 4; ++i) {
      float mn = fmaxf(mrow[i], mx[i]);
      scal[i] = __expf(mrow[i] - mn);
      mrow[i] = mn;
    }
    float rs[4] = {0.f, 0.f, 0.f, 0.f};
#pragma unroll
    for (int ct = 0; ct < 4; ++ct)
#pragma unroll
      for (int i = 0; i < 4; ++i) {
        float p = __expf(pv[ct][i] - mrow[i]);
        pv[ct][i] = p;
        rs[i] += p;
      }
#pragma unroll
    for (int off = 1; off < 16; off <<= 1)
#pragma unroll
      for (int i = 0; i < 4; ++i) rs[i] += __shfl_xor(rs[i], off, 64);
#pragma unroll
    for (int i = 0; i < 4; ++i) lrow[i] = lrow[i] * scal[i] + rs[i];
#pragma unroll
    for (int dt = 0; dt < 8; ++dt)
#pragma unroll
      for (int i = 0; i < 4; ++i) oacc[dt][i] *= scal[i];

    // ---- P -> LDS (bf16, swizzled)
#pragma unroll
    for (int ct = 0; ct < 4; ++ct)
#pragma unroll
      for (int i = 0; i < 4; ++i) {
        int row = lh * 4 + i;
        int cb = (ct * 16 + lr) * 2;
        *(unsigned short*)((char*)pw + ((row * 128 + cb) ^ ((row & 7) << 4))) = f2b(pv[ct][i]);
      }

    // ---- O += P V
#pragma unroll
    for (int ks = 0; ks < 2; ++ks) {
      int pcb = (ks * 32 + lh * 8) * 2;
      bf16x8 pf = *(const bf16x8*)((const char*)pw + ((lr * 128 + pcb) ^ ((lr & 7) << 4)));
#pragma unroll
      for (int dt = 0; dt < 8; ++dt) {
        int vrow = dt * 16 + lr;
        bf16x8 vf = *(const bf16x8*)((const char*)Vs + ((vrow * 128 + pcb) ^ ((vrow & 7) << 4)));
        oacc[dt] = __builtin_amdgcn_mfma_f32_16x16x32_bf16(pf, vf, oacc[dt], 0, 0, 0);
      }
    }
  }

  // ---- epilogue: O / l
#pragma unroll
  for (int i = 0; i < 4; ++i) {
    int qg = qt * 64 + w * 16 + lh * 4 + i;
    float inv = 1.0f / lrow[i];
#pragma unroll
    for (int dt = 0; dt < 8; ++dt)
      O[(size_t)qg * (NQH * HD) + h * HD + dt * 16 + lr] = f2b(oacc[dt][i] * inv);
  }
}

// ---------------------------------------------------------------------------
extern "C" void kernel_launch(void* const* d_in, const int* in_sizes, int n_in,
                              void* d_out, int out_size, void* d_ws, size_t ws_size,
                              hipStream_t stream) {
  const float* query = (const float*)d_in[0];
  const float* key = (const float*)d_in[1];
  const float* value = (const float*)d_in[2];
  // d_in[3] = mask (tril causal) -- causality is hardcoded
  const float* Wq = (const float*)d_in[4];
  const float* Wk = (const float*)d_in[5];
  const float* Wv = (const float*)d_in[6];
  const float* Wo = (const float*)d_in[7];
  float* out = (float*)d_out;

  char* ws = (char*)d_ws;
  // workspace layout (bytes)
  constexpr size_t OFF_WQT = 0;                       // 4096*4096*2 = 33554432
  constexpr size_t OFF_WOT = 33554432;                // 33554432
  constexpr size_t OFF_WKT = 67108864;                // 8388608
  constexpr size_t OFF_WVT = 75497472;                // 8388608
  constexpr size_t OFF_QB = 83886080;                 // 16777216
  constexpr size_t OFF_KB = 100663296;                // 16777216
  constexpr size_t OFF_VB = 117440512;                // 16777216
  constexpr size_t OFF_QP = 134217728;                // 16777216
  constexpr size_t OFF_KP = 150994944;                // 4194304
  constexpr size_t OFF_VP = 155189248;                // 4194304
  constexpr size_t OFF_VT = 159383552;                // 4194304
  constexpr size_t OFF_AT = 163577856;                // 16777216
  constexpr size_t WS_NEED = 180355072;
  if (ws_size < WS_NEED) return;

  unsigned short* WqT = (unsigned short*)(ws + OFF_WQT);
  unsigned short* WoT = (unsigned short*)(ws + OFF_WOT);
  unsigned short* WkT = (unsigned short*)(ws + OFF_WKT);
  unsigned short* WvT = (unsigned short*)(ws + OFF_WVT);
  unsigned short* qb = (unsigned short*)(ws + OFF_QB);
  unsigned short* kb = (unsigned short*)(ws + OFF_KB);
  unsigned short* vb = (unsigned short*)(ws + OFF_VB);
  unsigned short* Qp = (unsigned short*)(ws + OFF_QP);
  unsigned short* Kp = (unsigned short*)(ws + OFF_KP);
  unsigned short* Vp = (unsigned short*)(ws + OFF_VP);
  unsigned short* VTb = (unsigned short*)(ws + OFF_VT);
  unsigned short* attnb = (unsigned short*)(ws + OFF_AT);

  // 1) weight transpose+cast
  transpose_cast_kernel<<<dim3(64, 64), 256, 0, stream>>>(Wq, WqT, DM, NQH * HD);
  transpose_cast_kernel<<<dim3(64, 16), 256, 0, stream>>>(Wk, WkT, DM, NKVH * HD);
  transpose_cast_kernel<<<dim3(64, 16), 256, 0, stream>>>(Wv, WvT, DM, NKVH * HD);
  transpose_cast_kernel<<<dim3(64, 64), 256, 0, stream>>>(Wo, WoT, NQH * HD, DM);
  // 2) activation casts
  cast3_kernel<<<dim3(4096, 1, 3), 256, 0, stream>>>(query, key, value, qb, kb, vb);
  // 3) projections
  gemm_bt_kernel<false, false><<<dim3(32, 16, 1), 256, 0, stream>>>(
      qb, WqT, Qp, nullptr, nullptr, nullptr, T_SEQ, NQH * HD, DM);
  gemm_bt_kernel<false, true><<<dim3(8, 16, 2), 256, 0, stream>>>(
      kb, WkT, Kp, vb, WvT, Vp, T_SEQ, NKVH * HD, DM);
  // 4) RoPE (in place)
  rope_kernel<<<dim3(T_SEQ * NQH * 64 / 256), 256, 0, stream>>>(Qp, 5);
  rope_kernel<<<dim3(T_SEQ * NKVH * 64 / 256), 256, 0, stream>>>(Kp, 3);
  // 5) V transpose
  vtrans_kernel<<<dim3(NKVH * HD * T_SEQ / (256 * 8)), 256, 0, stream>>>(Vp, VTb);
  // 6) attention
  attn_kernel<<<dim3(T_SEQ / 64, NQH), 256, 0, stream>>>(Qp, Kp, VTb, attnb);
  // 7) output projection (fp32 out)
  gemm_bt_kernel<true, false><<<dim3(32, 16, 1), 256, 0, stream>>>(
      attnb, WoT, out, nullptr, nullptr, nullptr, T_SEQ, DM, DM);
}

// Round 2
// 582.126 us; speedup vs baseline: 1.1473x; 1.1473x over previous
//
#include <hip/hip_runtime.h>
#include <hip/hip_bf16.h>
#include <stdint.h>
#include <stddef.h>

// Problem constants
#define T_SEQ 2048
#define DM    4096
#define NQH   32
#define NKVH  8
#define HD    128
#define ATTN_MULT 0.08838834764831845f

typedef __attribute__((ext_vector_type(8))) short bf16x8;
typedef __attribute__((ext_vector_type(4))) float f32x4;
typedef __attribute__((ext_vector_type(4))) unsigned int u32x4;

__device__ __forceinline__ unsigned short f2b(float f) {
  unsigned u = __builtin_bit_cast(unsigned, f);
  u = u + 0x7FFFu + ((u >> 16) & 1u);
  return (unsigned short)(u >> 16);
}
__device__ __forceinline__ float b2f(unsigned short h) {
  unsigned u = ((unsigned)h) << 16;
  return __builtin_bit_cast(float, u);
}

typedef const __attribute__((address_space(1))) void* gptr1_t;
typedef __attribute__((address_space(3))) void* lptr3_t;
__device__ __forceinline__ void gl_lds16(const void* g, void* l) {
  __builtin_amdgcn_global_load_lds((gptr1_t)g, (lptr3_t)l, 16, 0, 0);
}

// ---------------------------------------------------------------------------
// Transpose + cast: W (K,N) f32 -> WT (N,K) bf16
// ---------------------------------------------------------------------------
__global__ __launch_bounds__(256) void transpose_cast_kernel(
    const float* __restrict__ W, unsigned short* __restrict__ WT, int K, int N) {
  __shared__ float tile[64][65];
  int k0 = blockIdx.x * 64;
  int n0 = blockIdx.y * 64;
  int t = threadIdx.x;
  int rr = t >> 4;   // 0..15
  int cc = t & 15;   // float4 column
#pragma unroll
  for (int c = 0; c < 4; ++c) {
    int row = c * 16 + rr;
    float4 v = *(const float4*)&W[(size_t)(k0 + row) * N + n0 + cc * 4];
    tile[row][cc * 4 + 0] = v.x;
    tile[row][cc * 4 + 1] = v.y;
    tile[row][cc * 4 + 2] = v.z;
    tile[row][cc * 4 + 3] = v.w;
  }
  __syncthreads();
  int orow = t >> 2;         // 0..63 (output row = original col)
  int kb = (t & 3) * 16;     // 16 k-values
  u32x4 o1, o2;
#pragma unroll
  for (int u = 0; u < 4; ++u) {
    o1[u] = (unsigned)f2b(tile[kb + 2 * u][orow]) |
            ((unsigned)f2b(tile[kb + 2 * u + 1][orow]) << 16);
    o2[u] = (unsigned)f2b(tile[kb + 8 + 2 * u][orow]) |
            ((unsigned)f2b(tile[kb + 9 + 2 * u][orow]) << 16);
  }
  unsigned short* dst = &WT[(size_t)(n0 + orow) * K + k0 + kb];
  *(u32x4*)dst = o1;
  *(u32x4*)(dst + 8) = o2;
}

// ---------------------------------------------------------------------------
// Cast 3 activation tensors f32 -> bf16 (each T_SEQ*DM elements)
// ---------------------------------------------------------------------------
__global__ __launch_bounds__(256) void cast3_kernel(
    const float* __restrict__ a0, const float* __restrict__ a1, const float* __restrict__ a2,
    unsigned short* __restrict__ b0, unsigned short* __restrict__ b1, unsigned short* __restrict__ b2) {
  const float* in = blockIdx.z == 0 ? a0 : (blockIdx.z == 1 ? a1 : a2);
  unsigned short* out = blockIdx.z == 0 ? b0 : (blockIdx.z == 1 ? b1 : b2);
  size_t idx = ((size_t)blockIdx.x * 256 + threadIdx.x) * 8;
  float4 x = *(const float4*)(in + idx);
  float4 y = *(const float4*)(in + idx + 4);
  u32x4 v;
  v[0] = (unsigned)f2b(x.x) | ((unsigned)f2b(x.y) << 16);
  v[1] = (unsigned)f2b(x.z) | ((unsigned)f2b(x.w) << 16);
  v[2] = (unsigned)f2b(y.x) | ((unsigned)f2b(y.y) << 16);
  v[3] = (unsigned)f2b(y.z) | ((unsigned)f2b(y.w) << 16);
  *(u32x4*)(out + idx) = v;
}

// ---------------------------------------------------------------------------
// GEMM: C(M,N) = A(M,K) * BT(N,K)^T   bf16 inputs, fp32 accum
// m97 structure + XCD-aware block swizzle (nwg % 8 == 0 for all launches)
// ---------------------------------------------------------------------------
template <bool F32OUT, bool DUAL>
__global__ __launch_bounds__(256) void gemm_bt_kernel(
    const unsigned short* __restrict__ A0, const unsigned short* __restrict__ B0, void* __restrict__ C0,
    const unsigned short* __restrict__ A1, const unsigned short* __restrict__ B1, void* __restrict__ C1,
    int M, int N, int K) {
  __shared__ unsigned short As[128 * 32];
  __shared__ unsigned short Bs[128 * 32];
  const unsigned short* A = A0;
  const unsigned short* BT = B0;
  void* C = C0;
  if (DUAL && blockIdx.z == 1) { A = A1; BT = B1; C = C1; }

  // XCD swizzle (bijective: nwg divisible by 8)
  int nx = gridDim.x;
  int flat = blockIdx.y * nx + blockIdx.x;
  int cpx = (nx * gridDim.y) >> 3;
  int swz = (flat & 7) * cpx + (flat >> 3);
  int m0 = (swz / nx) * 128;
  int n0 = (swz % nx) * 128;

  int t = threadIdx.x;
  int w = t >> 6, l = t & 63;
  int wr = w >> 1, wc = w & 1;
  int lr = l & 15, lh = l >> 4;

  f32x4 acc[4][4] = {};

  int srow0 = (w * 2 + 0) * 16 + (l >> 2);
  int srow1 = (w * 2 + 1) * 16 + (l >> 2);
  int scol = (l & 3) * 8;
  const unsigned short* Aa0 = A + (size_t)(m0 + srow0) * K + scol;
  const unsigned short* Aa1 = A + (size_t)(m0 + srow1) * K + scol;
  const unsigned short* Ba0 = BT + (size_t)(n0 + srow0) * K + scol;
  const unsigned short* Ba1 = BT + (size_t)(n0 + srow1) * K + scol;
  unsigned short* Al0 = &As[(w * 2 + 0) * 512];
  unsigned short* Al1 = &As[(w * 2 + 1) * 512];
  unsigned short* Bl0 = &Bs[(w * 2 + 0) * 512];
  unsigned short* Bl1 = &Bs[(w * 2 + 1) * 512];

  for (int k0 = 0; k0 < K; k0 += 32) {
    gl_lds16(Aa0 + k0, Al0);
    gl_lds16(Aa1 + k0, Al1);
    gl_lds16(Ba0 + k0, Bl0);
    gl_lds16(Ba1 + k0, Bl1);
    __syncthreads();
    bf16x8 af[4], bfr[4];
#pragma unroll
    for (int i = 0; i < 4; ++i)
      af[i] = *(const bf16x8*)&As[(wr * 64 + i * 16 + lr) * 32 + lh * 8];
#pragma unroll
    for (int j = 0; j < 4; ++j)
      bfr[j] = *(const bf16x8*)&Bs[(wc * 64 + j * 16 + lr) * 32 + lh * 8];
#pragma unroll
    for (int i = 0; i < 4; ++i)
#pragma unroll
      for (int j = 0; j < 4; ++j)
        acc[i][j] = __builtin_amdgcn_mfma_f32_16x16x32_bf16(af[i], bfr[j], acc[i][j], 0, 0, 0);
    __syncthreads();
  }

#pragma unroll
  for (int i = 0; i < 4; ++i) {
#pragma unroll
    for (int j = 0; j < 4; ++j) {
#pragma unroll
      for (int r = 0; r < 4; ++r) {
        int row = m0 + wr * 64 + i * 16 + lh * 4 + r;
        int col = n0 + wc * 64 + j * 16 + lr;
        if constexpr (F32OUT)
          ((float*)C)[(size_t)row * N + col] = acc[i][j][r];
        else
          ((unsigned short*)C)[(size_t)row * N + col] = f2b(acc[i][j][r]);
      }
    }
  }
}

// ---------------------------------------------------------------------------
// RoPE in place on (T, nheads*128) bf16.
// ---------------------------------------------------------------------------
__global__ __launch_bounds__(256) void rope_kernel(unsigned short* __restrict__ X, int hshift) {
  int nheads = 1 << hshift;
  int idx = blockIdx.x * 256 + threadIdx.x;
  int i = idx & 63;
  int rest = idx >> 6;
  int hh = rest & (nheads - 1);
  int tpos = rest >> hshift;
  float invf = exp2f(-(float)i * (13.287712379549449f / 64.0f));
  float phase = (float)tpos * invf;
  float s, c;
  sincosf(phase, &s, &c);
  size_t base = (size_t)tpos * ((size_t)nheads * HD) + (size_t)hh * HD + i;
  float x1 = b2f(X[base]);
  float x2 = b2f(X[base + 64]);
  X[base] = f2b(x1 * c - x2 * s);
  X[base + 64] = f2b(x2 * c + x1 * s);
}

// ---------------------------------------------------------------------------
// V (T, NKVH*HD) bf16 -> VT (NKVH, HD, T) bf16
// ---------------------------------------------------------------------------
__global__ __launch_bounds__(256) void vtrans_kernel(
    const unsigned short* __restrict__ V, unsigned short* __restrict__ VT) {
  size_t flat = ((size_t)blockIdx.x * 256 + threadIdx.x) * 8;
  int t8 = (int)(flat & (T_SEQ - 1));
  int dh = (int)(flat >> 11);  // kvh*HD + d
  u32x4 v;
#pragma unroll
  for (int u = 0; u < 4; ++u) {
    unsigned short lo = V[(size_t)(t8 + 2 * u) * (NKVH * HD) + dh];
    unsigned short hi = V[(size_t)(t8 + 2 * u + 1) * (NKVH * HD) + dh];
    v[u] = (unsigned)lo | ((unsigned)hi << 16);
  }
  *(u32x4*)(VT + flat) = v;
}

// ---------------------------------------------------------------------------
// Flash attention v2: 8 waves, 2 q-heads/block (shared kv-head), 64 q-rows,
// KV tiles of 64, double-buffered K/V staging (prefetch before compute),
// FIXED-max softmax: tanh-cap bounds logits <= 30, so p = exp(x-30) directly;
// no online max, no rescale, row-sum reduced once in epilogue.
// ---------------------------------------------------------------------------
__global__ __launch_bounds__(512) void attn_kernel(
    const unsigned short* __restrict__ Q,   // (T, NQH*HD) roped
    const unsigned short* __restrict__ Kx,  // (T, NKVH*HD) roped
    const unsigned short* __restrict__ VT,  // (NKVH, HD, T)
    unsigned short* __restrict__ O) {       // (T, NQH*HD)
  __shared__ unsigned short Ks[2][64 * 128];
  __shared__ unsigned short Vs[2][128 * 64];
  __shared__ unsigned short Ps[8][16 * 64];

  int qt = (gridDim.x - 1) - blockIdx.x;  // heaviest causal blocks first
  int by = blockIdx.y;                    // head pair 0..15
  int t = threadIdx.x;
  int w = t >> 6, l = t & 63;
  int wq = w & 3;                         // q sub-tile within the 64 rows
  int hh = by * 2 + (w >> 2);             // this wave's q-head
  int kvh = by >> 1;
  int lr = l & 15, lh = l >> 4;

  // softcap+softmax constants: logits = 30*tanh(s*ATTN_MULT/30) <= 30
  // p = exp(logit - 30) = exp2(C2 / (exp2(s*C1) + 1))
  constexpr float C1 = (float)(0.08838834764831845 * 1.4426950408889634 / 15.0);
  constexpr float C2 = (float)(-60.0 * 1.4426950408889634);

  // Q fragments (registers for whole block)
  bf16x8 qf[4];
  int qrow = qt * 64 + wq * 16 + lr;
  const unsigned short* qp = Q + (size_t)qrow * (NQH * HD) + hh * HD + lh * 8;
#pragma unroll
  for (int kk = 0; kk < 4; ++kk) qf[kk] = *(const bf16x8*)(qp + kk * 32);

  f32x4 oacc[8] = {};
  float lsum[4] = {0.f, 0.f, 0.f, 0.f};

  const char* KgB = (const char*)Kx + (size_t)kvh * HD * 2;
  const char* VgB = (const char*)VT + (size_t)kvh * HD * T_SEQ * 2;
  unsigned short* pw = Ps[w];

  // stage tile kt into buffer b: 8 waves x (2 K-chunks + 2 V-chunks) of 1KB
  auto stage = [&](int kt, int b) {
#pragma unroll
    for (int c = 0; c < 2; ++c) {
      int chunk = w * 2 + c;
      int p = chunk * 1024 + l * 16;
      {
        int row = p >> 8;                 // key in tile
        int cb = p & 255;
        int cbl = cb ^ ((row & 7) << 4);  // pre-swizzled global source
        gl_lds16(KgB + (size_t)(kt * 64 + row) * (NKVH * HD * 2) + cbl,
                 (char*)Ks[b] + chunk * 1024);
      }
      {
        int row = p >> 7;                 // d
        int cb = p & 127;
        int cbl = cb ^ ((row & 7) << 4);
        gl_lds16(VgB + (size_t)row * (T_SEQ * 2) + (size_t)kt * 128 + cbl,
                 (char*)Vs[b] + chunk * 1024);
      }
    }
  };

  stage(0, 0);
  __syncthreads();  // compiler drains vmcnt(0) before the barrier

  int cur = 0;
  for (int kt = 0; kt <= qt; ++kt) {
    if (kt < qt) stage(kt + 1, cur ^ 1);  // prefetch overlaps compute below

    // ---- S = Q K^T
    f32x4 sa[4];
#pragma unroll
    for (int ct = 0; ct < 4; ++ct) {
      f32x4 z = {};
#pragma unroll
      for (int kk = 0; kk < 4; ++kk) {
        int row = ct * 16 + lr;
        int cb = (kk * 32 + lh * 8) * 2;
        bf16x8 kf = *(const bf16x8*)((const char*)Ks[cur] + row * 256 + (cb ^ ((row & 7) << 4)));
        z = __builtin_amdgcn_mfma_f32_16x16x32_bf16(qf[kk], kf, z, 0, 0, 0);
      }
      sa[ct] = z;
    }

    // ---- softcap + fixed-max softmax (mask only on diagonal tile)
    float pv[4][4];
    if (kt == qt) {
#pragma unroll
      for (int ct = 0; ct < 4; ++ct)
#pragma unroll
        for (int i = 0; i < 4; ++i) {
          float u = exp2f(sa[ct][i] * C1);
          float p = exp2f(C2 * __builtin_amdgcn_rcpf(u + 1.0f));
          int kg = ct * 16 + lr;
          int qg = wq * 16 + lh * 4 + i;
          pv[ct][i] = (kg > qg) ? 0.0f : p;
        }
    } else {
#pragma unroll
      for (int ct = 0; ct < 4; ++ct)
#pragma unroll
        for (int i = 0; i < 4; ++i) {
          float u = exp2f(sa[ct][i] * C1);
          pv[ct][i] = exp2f(C2 * __builtin_amdgcn_rcpf(u + 1.0f));
        }
    }
#pragma unroll
    for (int ct = 0; ct < 4; ++ct)
#pragma unroll
      for (int i = 0; i < 4; ++i) lsum[i] += pv[ct][i];

    // ---- P -> LDS (bf16, swizzled, per-wave buffer)
#pragma unroll
    for (int ct = 0; ct < 4; ++ct)
#pragma unroll
      for (int i = 0; i < 4; ++i) {
        int row = lh * 4 + i;
        int cb = (ct * 16 + lr) * 2;
        *(unsigned short*)((char*)pw + ((row * 128 + cb) ^ ((row & 7) << 4))) = f2b(pv[ct][i]);
      }

    // ---- O += P V
#pragma unroll
    for (int ks = 0; ks < 2; ++ks) {
      int pcb = (ks * 32 + lh * 8) * 2;
      bf16x8 pf = *(const bf16x8*)((const char*)pw + ((lr * 128 + pcb) ^ ((lr & 7) << 4)));
#pragma unroll
      for (int dt = 0; dt < 8; ++dt) {
        int vrow = dt * 16 + lr;
        bf16x8 vf = *(const bf16x8*)((const char*)Vs[cur] + ((vrow * 128 + pcb) ^ ((vrow & 7) << 4)));
        oacc[dt] = __builtin_amdgcn_mfma_f32_16x16x32_bf16(pf, vf, oacc[dt], 0, 0, 0);
      }
    }

    __syncthreads();  // vmcnt(0) drain lands AFTER compute; publish next buffer
    cur ^= 1;
  }

  // ---- epilogue: reduce row-sums across the 16 key-lanes, then O / l
#pragma unroll
  for (int off = 1; off < 16; off <<= 1)
#pragma unroll
    for (int i = 0; i < 4; ++i) lsum[i] += __shfl_xor(lsum[i], off, 64);

#pragma unroll
  for (int i = 0; i < 4; ++i) {
    int qg = qt * 64 + wq * 16 + lh * 4 + i;
    float inv = 1.0f / lsum[i];
#pragma unroll
    for (int dt = 0; dt < 8; ++dt)
      O[(size_t)qg * (NQH * HD) + hh * HD + dt * 16 + lr] = f2b(oacc[dt][i] * inv);
  }
}

// ---------------------------------------------------------------------------
extern "C" void kernel_launch(void* const* d_in, const int* in_sizes, int n_in,
                              void* d_out, int out_size, void* d_ws, size_t ws_size,
                              hipStream_t stream) {
  const float* query = (const float*)d_in[0];
  const float* key = (const float*)d_in[1];
  const float* value = (const float*)d_in[2];
  // d_in[3] = mask (tril causal) -- causality is hardcoded
  const float* Wq = (const float*)d_in[4];
  const float* Wk = (const float*)d_in[5];
  const float* Wv = (const float*)d_in[6];
  const float* Wo = (const float*)d_in[7];
  float* out = (float*)d_out;

  char* ws = (char*)d_ws;
  constexpr size_t OFF_WQT = 0;
  constexpr size_t OFF_WOT = 33554432;
  constexpr size_t OFF_WKT = 67108864;
  constexpr size_t OFF_WVT = 75497472;
  constexpr size_t OFF_QB = 83886080;
  constexpr size_t OFF_KB = 100663296;
  constexpr size_t OFF_VB = 117440512;
  constexpr size_t OFF_QP = 134217728;
  constexpr size_t OFF_KP = 150994944;
  constexpr size_t OFF_VP = 155189248;
  constexpr size_t OFF_VT = 159383552;
  constexpr size_t OFF_AT = 163577856;
  constexpr size_t WS_NEED = 180355072;
  if (ws_size < WS_NEED) return;

  unsigned short* WqT = (unsigned short*)(ws + OFF_WQT);
  unsigned short* WoT = (unsigned short*)(ws + OFF_WOT);
  unsigned short* WkT = (unsigned short*)(ws + OFF_WKT);
  unsigned short* WvT = (unsigned short*)(ws + OFF_WVT);
  unsigned short* qb = (unsigned short*)(ws + OFF_QB);
  unsigned short* kb = (unsigned short*)(ws + OFF_KB);
  unsigned short* vb = (unsigned short*)(ws + OFF_VB);
  unsigned short* Qp = (unsigned short*)(ws + OFF_QP);
  unsigned short* Kp = (unsigned short*)(ws + OFF_KP);
  unsigned short* Vp = (unsigned short*)(ws + OFF_VP);
  unsigned short* VTb = (unsigned short*)(ws + OFF_VT);
  unsigned short* attnb = (unsigned short*)(ws + OFF_AT);

  transpose_cast_kernel<<<dim3(64, 64), 256, 0, stream>>>(Wq, WqT, DM, NQH * HD);
  transpose_cast_kernel<<<dim3(64, 16), 256, 0, stream>>>(Wk, WkT, DM, NKVH * HD);
  transpose_cast_kernel<<<dim3(64, 16), 256, 0, stream>>>(Wv, WvT, DM, NKVH * HD);
  transpose_cast_kernel<<<dim3(64, 64), 256, 0, stream>>>(Wo, WoT, NQH * HD, DM);
  cast3_kernel<<<dim3(4096, 1, 3), 256, 0, stream>>>(query, key, value, qb, kb, vb);
  gemm_bt_kernel<false, false><<<dim3(32, 16, 1), 256, 0, stream>>>(
      qb, WqT, Qp, nullptr, nullptr, nullptr, T_SEQ, NQH * HD, DM);
  gemm_bt_kernel<false, true><<<dim3(8, 16, 2), 256, 0, stream>>>(
      kb, WkT, Kp, vb, WvT, Vp, T_SEQ, NKVH * HD, DM);
  rope_kernel<<<dim3(T_SEQ * NQH * 64 / 256), 256, 0, stream>>>(Qp, 5);
  rope_kernel<<<dim3(T_SEQ * NKVH * 64 / 256), 256, 0, stream>>>(Kp, 3);
  vtrans_kernel<<<dim3(NKVH * HD * T_SEQ / (256 * 8)), 256, 0, stream>>>(Vp, VTb);
  attn_kernel<<<dim3(T_SEQ / 64, NQH / 2), 512, 0, stream>>>(Qp, Kp, VTb, attnb);
  gemm_bt_kernel<true, false><<<dim3(32, 16, 1), 256, 0, stream>>>(
      attnb, WoT, out, nullptr, nullptr, nullptr, T_SEQ, DM, DM);
}

// Round 3
// 496.338 us; speedup vs baseline: 1.3457x; 1.1728x over previous
//
#include <hip/hip_runtime.h>
#include <hip/hip_bf16.h>
#include <stdint.h>
#include <stddef.h>

// Problem constants
#define T_SEQ 2048
#define DM    4096
#define NQH   32
#define NKVH  8
#define HD    128
#define ATTN_MULT 0.08838834764831845f

typedef __attribute__((ext_vector_type(8))) short bf16x8;
typedef __attribute__((ext_vector_type(4))) float f32x4;
typedef __attribute__((ext_vector_type(4))) unsigned int u32x4;

__device__ __forceinline__ unsigned short f2b(float f) {
  unsigned u = __builtin_bit_cast(unsigned, f);
  u = u + 0x7FFFu + ((u >> 16) & 1u);
  return (unsigned short)(u >> 16);
}
__device__ __forceinline__ float b2f(unsigned short h) {
  unsigned u = ((unsigned)h) << 16;
  return __builtin_bit_cast(float, u);
}

typedef const __attribute__((address_space(1))) void* gptr1_t;
typedef __attribute__((address_space(3))) void* lptr3_t;
__device__ __forceinline__ void gl_lds16(const void* g, void* l) {
  __builtin_amdgcn_global_load_lds((gptr1_t)g, (lptr3_t)l, 16, 0, 0);
}

// ---------------------------------------------------------------------------
// Transpose + cast: W (K,N) f32 -> WT (N,K) bf16
// ---------------------------------------------------------------------------
__global__ __launch_bounds__(256) void transpose_cast_kernel(
    const float* __restrict__ W, unsigned short* __restrict__ WT, int K, int N) {
  __shared__ float tile[64][65];
  int k0 = blockIdx.x * 64;
  int n0 = blockIdx.y * 64;
  int t = threadIdx.x;
  int rr = t >> 4;
  int cc = t & 15;
#pragma unroll
  for (int c = 0; c < 4; ++c) {
    int row = c * 16 + rr;
    float4 v = *(const float4*)&W[(size_t)(k0 + row) * N + n0 + cc * 4];
    tile[row][cc * 4 + 0] = v.x;
    tile[row][cc * 4 + 1] = v.y;
    tile[row][cc * 4 + 2] = v.z;
    tile[row][cc * 4 + 3] = v.w;
  }
  __syncthreads();
  int orow = t >> 2;
  int kb = (t & 3) * 16;
  u32x4 o1, o2;
#pragma unroll
  for (int u = 0; u < 4; ++u) {
    o1[u] = (unsigned)f2b(tile[kb + 2 * u][orow]) |
            ((unsigned)f2b(tile[kb + 2 * u + 1][orow]) << 16);
    o2[u] = (unsigned)f2b(tile[kb + 8 + 2 * u][orow]) |
            ((unsigned)f2b(tile[kb + 9 + 2 * u][orow]) << 16);
  }
  unsigned short* dst = &WT[(size_t)(n0 + orow) * K + k0 + kb];
  *(u32x4*)dst = o1;
  *(u32x4*)(dst + 8) = o2;
}

// ---------------------------------------------------------------------------
// Cast 3 activation tensors f32 -> bf16
// ---------------------------------------------------------------------------
__global__ __launch_bounds__(256) void cast3_kernel(
    const float* __restrict__ a0, const float* __restrict__ a1, const float* __restrict__ a2,
    unsigned short* __restrict__ b0, unsigned short* __restrict__ b1, unsigned short* __restrict__ b2) {
  const float* in = blockIdx.z == 0 ? a0 : (blockIdx.z == 1 ? a1 : a2);
  unsigned short* out = blockIdx.z == 0 ? b0 : (blockIdx.z == 1 ? b1 : b2);
  size_t idx = ((size_t)blockIdx.x * 256 + threadIdx.x) * 8;
  float4 x = *(const float4*)(in + idx);
  float4 y = *(const float4*)(in + idx + 4);
  u32x4 v;
  v[0] = (unsigned)f2b(x.x) | ((unsigned)f2b(x.y) << 16);
  v[1] = (unsigned)f2b(x.z) | ((unsigned)f2b(x.w) << 16);
  v[2] = (unsigned)f2b(y.x) | ((unsigned)f2b(y.y) << 16);
  v[3] = (unsigned)f2b(y.z) | ((unsigned)f2b(y.w) << 16);
  *(u32x4*)(out + idx) = v;
}

// ---------------------------------------------------------------------------
// GEMM: C(M,N) = A(M,K) * BT(N,K)^T   bf16 in, fp32 accum (m97 + XCD swizzle)
// ---------------------------------------------------------------------------
template <bool F32OUT, bool DUAL>
__global__ __launch_bounds__(256) void gemm_bt_kernel(
    const unsigned short* __restrict__ A0, const unsigned short* __restrict__ B0, void* __restrict__ C0,
    const unsigned short* __restrict__ A1, const unsigned short* __restrict__ B1, void* __restrict__ C1,
    int M, int N, int K) {
  __shared__ unsigned short As[128 * 32];
  __shared__ unsigned short Bs[128 * 32];
  const unsigned short* A = A0;
  const unsigned short* BT = B0;
  void* C = C0;
  if (DUAL && blockIdx.z == 1) { A = A1; BT = B1; C = C1; }

  int nx = gridDim.x;
  int flat = blockIdx.y * nx + blockIdx.x;
  int cpx = (nx * gridDim.y) >> 3;
  int swz = (flat & 7) * cpx + (flat >> 3);
  int m0 = (swz / nx) * 128;
  int n0 = (swz % nx) * 128;

  int t = threadIdx.x;
  int w = t >> 6, l = t & 63;
  int wr = w >> 1, wc = w & 1;
  int lr = l & 15, lh = l >> 4;

  f32x4 acc[4][4] = {};

  int srow0 = (w * 2 + 0) * 16 + (l >> 2);
  int srow1 = (w * 2 + 1) * 16 + (l >> 2);
  int scol = (l & 3) * 8;
  const unsigned short* Aa0 = A + (size_t)(m0 + srow0) * K + scol;
  const unsigned short* Aa1 = A + (size_t)(m0 + srow1) * K + scol;
  const unsigned short* Ba0 = BT + (size_t)(n0 + srow0) * K + scol;
  const unsigned short* Ba1 = BT + (size_t)(n0 + srow1) * K + scol;
  unsigned short* Al0 = &As[(w * 2 + 0) * 512];
  unsigned short* Al1 = &As[(w * 2 + 1) * 512];
  unsigned short* Bl0 = &Bs[(w * 2 + 0) * 512];
  unsigned short* Bl1 = &Bs[(w * 2 + 1) * 512];

  for (int k0 = 0; k0 < K; k0 += 32) {
    gl_lds16(Aa0 + k0, Al0);
    gl_lds16(Aa1 + k0, Al1);
    gl_lds16(Ba0 + k0, Bl0);
    gl_lds16(Ba1 + k0, Bl1);
    __syncthreads();
    bf16x8 af[4], bfr[4];
#pragma unroll
    for (int i = 0; i < 4; ++i)
      af[i] = *(const bf16x8*)&As[(wr * 64 + i * 16 + lr) * 32 + lh * 8];
#pragma unroll
    for (int j = 0; j < 4; ++j)
      bfr[j] = *(const bf16x8*)&Bs[(wc * 64 + j * 16 + lr) * 32 + lh * 8];
#pragma unroll
    for (int i = 0; i < 4; ++i)
#pragma unroll
      for (int j = 0; j < 4; ++j)
        acc[i][j] = __builtin_amdgcn_mfma_f32_16x16x32_bf16(af[i], bfr[j], acc[i][j], 0, 0, 0);
    __syncthreads();
  }

#pragma unroll
  for (int i = 0; i < 4; ++i) {
#pragma unroll
    for (int j = 0; j < 4; ++j) {
#pragma unroll
      for (int r = 0; r < 4; ++r) {
        int row = m0 + wr * 64 + i * 16 + lh * 4 + r;
        int col = n0 + wc * 64 + j * 16 + lr;
        if constexpr (F32OUT)
          ((float*)C)[(size_t)row * N + col] = acc[i][j][r];
        else
          ((unsigned short*)C)[(size_t)row * N + col] = f2b(acc[i][j][r]);
      }
    }
  }
}

// ---------------------------------------------------------------------------
// sincos table: tab[t*64+i] = (cos, sin) of pos t, freq i
// ---------------------------------------------------------------------------
__global__ __launch_bounds__(256) void sincos_kernel(float2* __restrict__ tab) {
  int idx = blockIdx.x * 256 + threadIdx.x;
  int i = idx & 63;
  int tpos = idx >> 6;
  float invf = exp2f(-(float)i * (13.287712379549449f / 64.0f));
  float phase = (float)tpos * invf;
  float s, c;
  sincosf(phase, &s, &c);
  tab[idx] = make_float2(c, s);
}

// ---------------------------------------------------------------------------
// RoPE in place on (T, nheads*128) bf16, with output scale (C1 folded into Q)
// ---------------------------------------------------------------------------
__global__ __launch_bounds__(256) void rope_kernel(unsigned short* __restrict__ X,
                                                   const float2* __restrict__ tab,
                                                   int hshift, float scale) {
  int idx = blockIdx.x * 256 + threadIdx.x;
  int i = idx & 63;
  int rest = idx >> 6;
  int nheads = 1 << hshift;
  int hh = rest & (nheads - 1);
  int tpos = rest >> hshift;
  float2 cs = tab[tpos * 64 + i];
  size_t base = (size_t)tpos * ((size_t)nheads * HD) + (size_t)hh * HD + i;
  float x1 = b2f(X[base]);
  float x2 = b2f(X[base + 64]);
  X[base] = f2b((x1 * cs.x - x2 * cs.y) * scale);
  X[base + 64] = f2b((x2 * cs.x + x1 * cs.y) * scale);
}

// ---------------------------------------------------------------------------
// V (T, NKVH*HD) bf16 -> VT (NKVH, HD, T) bf16
// ---------------------------------------------------------------------------
__global__ __launch_bounds__(256) void vtrans_kernel(
    const unsigned short* __restrict__ V, unsigned short* __restrict__ VT) {
  size_t flat = ((size_t)blockIdx.x * 256 + threadIdx.x) * 8;
  int t8 = (int)(flat & (T_SEQ - 1));
  int dh = (int)(flat >> 11);
  u32x4 v;
#pragma unroll
  for (int u = 0; u < 4; ++u) {
    unsigned short lo = V[(size_t)(t8 + 2 * u) * (NKVH * HD) + dh];
    unsigned short hi = V[(size_t)(t8 + 2 * u + 1) * (NKVH * HD) + dh];
    v[u] = (unsigned)lo | ((unsigned)hi << 16);
  }
  *(u32x4*)(VT + flat) = v;
}

// ---------------------------------------------------------------------------
// Attention v3 helpers
// S^T layout (from mfma(kf,qf)): lane holds P[q = lane&15][k = 16ct+4lh+r].
// softmax_frag: softcap+exp (fixed max 30), lane-local row sum, pack to bf16,
// __shfl-redistribute into PV A-fragments pf[2] (lane: P[q=lr][k=32ks+8lh+e]).
// ---------------------------------------------------------------------------
template <bool DIAG>
__device__ __forceinline__ void softmax_frag(const f32x4 s[4], float& lsum, bf16x8 pf[2],
                                             int lr, int lh, int wq) {
  constexpr float C2f = (float)(-60.0 * 1.4426950408889634);
  float pv[4][4];
#pragma unroll
  for (int ct = 0; ct < 4; ++ct)
#pragma unroll
    for (int r = 0; r < 4; ++r) {
      // Q pre-scaled by C1 = ATTN_MULT*log2e/15 -> u = 2^(logit*log2e/15)
      float u = exp2f(s[ct][r]);
      float p = exp2f(C2f * __builtin_amdgcn_rcpf(u + 1.0f));
      if constexpr (DIAG) {
        int kg = ct * 16 + lh * 4 + r;
        int qg = wq * 16 + lr;
        if (kg > qg) p = 0.0f;
      }
      pv[ct][r] = p;
      lsum += p;
    }
  unsigned pk[4][2];
#pragma unroll
  for (int ct = 0; ct < 4; ++ct) {
    pk[ct][0] = (unsigned)f2b(pv[ct][0]) | ((unsigned)f2b(pv[ct][1]) << 16);
    pk[ct][1] = (unsigned)f2b(pv[ct][2]) | ((unsigned)f2b(pv[ct][3]) << 16);
  }
  int s0 = ((lh & 1) << 5) + lr;  // src lane for words 0,1
  int s1 = s0 + 16;               // src lane for words 2,3
  bool hi = (lh >= 2);
#pragma unroll
  for (int ks = 0; ks < 2; ++ks) {
    unsigned a0 = (unsigned)__shfl((int)pk[2 * ks][0], s0, 64);
    unsigned a1 = (unsigned)__shfl((int)pk[2 * ks][1], s0, 64);
    unsigned a2 = (unsigned)__shfl((int)pk[2 * ks][0], s1, 64);
    unsigned a3 = (unsigned)__shfl((int)pk[2 * ks][1], s1, 64);
    unsigned b0 = (unsigned)__shfl((int)pk[2 * ks + 1][0], s0, 64);
    unsigned b1 = (unsigned)__shfl((int)pk[2 * ks + 1][1], s0, 64);
    unsigned b2 = (unsigned)__shfl((int)pk[2 * ks + 1][0], s1, 64);
    unsigned b3 = (unsigned)__shfl((int)pk[2 * ks + 1][1], s1, 64);
    u32x4 f;
    f[0] = hi ? b0 : a0;
    f[1] = hi ? b1 : a1;
    f[2] = hi ? b2 : a2;
    f[3] = hi ? b3 : a3;
    pf[ks] = __builtin_bit_cast(bf16x8, f);
  }
}

template <bool WITHA, bool DIAGA, bool DIAGB>
__device__ __forceinline__ void attn_tile(
    const char* KsCur, const char* VsCur,
    const bf16x8 qfA[4], const bf16x8 qfB[4],
    f32x4 oaccA[8], f32x4 oaccB[8],
    float& lsumA, float& lsumB,
    int lr, int lh, int wq) {
  f32x4 sB[4], sA[4];
#pragma unroll
  for (int ct = 0; ct < 4; ++ct) {
    f32x4 zB = {};
    f32x4 zA = {};
#pragma unroll
    for (int kk = 0; kk < 4; ++kk) {
      int row = ct * 16 + lr;
      int cb = (kk * 32 + lh * 8) * 2;
      bf16x8 kf = *(const bf16x8*)(KsCur + row * 256 + (cb ^ ((row & 7) << 4)));
      zB = __builtin_amdgcn_mfma_f32_16x16x32_bf16(kf, qfB[kk], zB, 0, 0, 0);
      if constexpr (WITHA) zA = __builtin_amdgcn_mfma_f32_16x16x32_bf16(kf, qfA[kk], zA, 0, 0, 0);
    }
    sB[ct] = zB;
    if constexpr (WITHA) sA[ct] = zA;
  }
  bf16x8 pfB[2], pfA[2];
  softmax_frag<DIAGB>(sB, lsumB, pfB, lr, lh, wq);
  if constexpr (WITHA) softmax_frag<DIAGA>(sA, lsumA, pfA, lr, lh, wq);
#pragma unroll
  for (int ks = 0; ks < 2; ++ks) {
    int pcb = (ks * 32 + lh * 8) * 2;
#pragma unroll
    for (int dt = 0; dt < 8; ++dt) {
      int vrow = dt * 16 + lr;
      bf16x8 vf = *(const bf16x8*)(VsCur + ((vrow * 128 + pcb) ^ ((vrow & 7) << 4)));
      oaccB[dt] = __builtin_amdgcn_mfma_f32_16x16x32_bf16(pfB[ks], vf, oaccB[dt], 0, 0, 0);
      if constexpr (WITHA) oaccA[dt] = __builtin_amdgcn_mfma_f32_16x16x32_bf16(pfA[ks], vf, oaccA[dt], 0, 0, 0);
    }
  }
}

// ---------------------------------------------------------------------------
// Flash attention v3: folded q-tile pairs (qtA=bx, qtB=31-bx), 2 heads/block
// (shared kv-head), 8 waves, KV tiles of 64 double-buffered, P in registers.
// Every block does exactly 33 tile-units -> perfect balance. LDS = 64 KB.
// ---------------------------------------------------------------------------
__global__ __launch_bounds__(512, 2) void attn_kernel(
    const unsigned short* __restrict__ Q,   // (T, NQH*HD) roped, pre-scaled C1
    const unsigned short* __restrict__ Kx,  // (T, NKVH*HD) roped
    const unsigned short* __restrict__ VT,  // (NKVH, HD, T)
    unsigned short* __restrict__ O) {       // (T, NQH*HD)
  __shared__ unsigned short Ks[2][64 * 128];
  __shared__ unsigned short Vs[2][128 * 64];

  int bx = blockIdx.x;  // fold 0..15
  int by = blockIdx.y;  // head pair 0..15
  int qtA = bx, qtB = 31 - bx;
  int t = threadIdx.x;
  int w = t >> 6, l = t & 63;
  int wq = w & 3;
  int hh = by * 2 + (w >> 2);
  int kvh = by >> 1;
  int lr = l & 15, lh = l >> 4;

  // Q fragments for both q-tiles
  bf16x8 qfA[4], qfB[4];
  {
    const unsigned short* qpA = Q + (size_t)(qtA * 64 + wq * 16 + lr) * (NQH * HD) + hh * HD + lh * 8;
    const unsigned short* qpB = Q + (size_t)(qtB * 64 + wq * 16 + lr) * (NQH * HD) + hh * HD + lh * 8;
#pragma unroll
    for (int kk = 0; kk < 4; ++kk) {
      qfA[kk] = *(const bf16x8*)(qpA + kk * 32);
      qfB[kk] = *(const bf16x8*)(qpB + kk * 32);
    }
  }

  f32x4 oaccA[8] = {}, oaccB[8] = {};
  float lsumA = 0.f, lsumB = 0.f;

  const char* KgB = (const char*)Kx + (size_t)kvh * HD * 2;
  const char* VgB = (const char*)VT + (size_t)kvh * HD * T_SEQ * 2;

  auto stage = [&](int kt, int b) {
#pragma unroll
    for (int c = 0; c < 2; ++c) {
      int chunk = w * 2 + c;
      int p = chunk * 1024 + l * 16;
      {
        int row = p >> 8;
        int cb = p & 255;
        int cbl = cb ^ ((row & 7) << 4);
        gl_lds16(KgB + (size_t)(kt * 64 + row) * (NKVH * HD * 2) + cbl,
                 (char*)Ks[b] + chunk * 1024);
      }
      {
        int row = p >> 7;
        int cb = p & 127;
        int cbl = cb ^ ((row & 7) << 4);
        gl_lds16(VgB + (size_t)row * (T_SEQ * 2) + (size_t)kt * 128 + cbl,
                 (char*)Vs[b] + chunk * 1024);
      }
    }
  };

  stage(0, 0);
  __syncthreads();

  int cur = 0;
  for (int kt = 0; kt <= qtB; ++kt) {
    if (kt < qtB) stage(kt + 1, cur ^ 1);  // prefetch overlaps compute
    const char* Kc = (const char*)Ks[cur];
    const char* Vc = (const char*)Vs[cur];
    if (kt < qtA)
      attn_tile<true, false, false>(Kc, Vc, qfA, qfB, oaccA, oaccB, lsumA, lsumB, lr, lh, wq);
    else if (kt == qtA)
      attn_tile<true, true, false>(Kc, Vc, qfA, qfB, oaccA, oaccB, lsumA, lsumB, lr, lh, wq);
    else if (kt < qtB)
      attn_tile<false, false, false>(Kc, Vc, qfA, qfB, oaccA, oaccB, lsumA, lsumB, lr, lh, wq);
    else
      attn_tile<false, false, true>(Kc, Vc, qfA, qfB, oaccA, oaccB, lsumA, lsumB, lr, lh, wq);
    __syncthreads();  // vmcnt(0) drain lands after compute; publish next buffer
    cur ^= 1;
  }

  // reduce lane-local row sums across the 4 lh groups (same q=lr)
  lsumB += __shfl_xor(lsumB, 16, 64);
  lsumB += __shfl_xor(lsumB, 32, 64);
  lsumA += __shfl_xor(lsumA, 16, 64);
  lsumA += __shfl_xor(lsumA, 32, 64);

#pragma unroll
  for (int i = 0; i < 4; ++i) {
    int srcl = (l & 48) | (lh * 4 + i);  // lane holding lsum for q = lh*4+i
    float invB = 1.0f / __shfl(lsumB, srcl, 64);
    float invA = 1.0f / __shfl(lsumA, srcl, 64);
    int qgB = qtB * 64 + wq * 16 + lh * 4 + i;
    int qgA = qtA * 64 + wq * 16 + lh * 4 + i;
#pragma unroll
    for (int dt = 0; dt < 8; ++dt) {
      O[(size_t)qgB * (NQH * HD) + hh * HD + dt * 16 + lr] = f2b(oaccB[dt][i] * invB);
      O[(size_t)qgA * (NQH * HD) + hh * HD + dt * 16 + lr] = f2b(oaccA[dt][i] * invA);
    }
  }
}

// ---------------------------------------------------------------------------
extern "C" void kernel_launch(void* const* d_in, const int* in_sizes, int n_in,
                              void* d_out, int out_size, void* d_ws, size_t ws_size,
                              hipStream_t stream) {
  const float* query = (const float*)d_in[0];
  const float* key = (const float*)d_in[1];
  const float* value = (const float*)d_in[2];
  // d_in[3] = mask (tril causal) -- hardcoded
  const float* Wq = (const float*)d_in[4];
  const float* Wk = (const float*)d_in[5];
  const float* Wv = (const float*)d_in[6];
  const float* Wo = (const float*)d_in[7];
  float* out = (float*)d_out;

  char* ws = (char*)d_ws;
  constexpr size_t OFF_WQT = 0;
  constexpr size_t OFF_WOT = 33554432;
  constexpr size_t OFF_WKT = 67108864;
  constexpr size_t OFF_WVT = 75497472;
  constexpr size_t OFF_QB = 83886080;
  constexpr size_t OFF_KB = 100663296;
  constexpr size_t OFF_VB = 117440512;
  constexpr size_t OFF_QP = 134217728;
  constexpr size_t OFF_KP = 150994944;
  constexpr size_t OFF_VP = 155189248;
  constexpr size_t OFF_VT = 159383552;
  constexpr size_t OFF_AT = 163577856;
  constexpr size_t WS_NEED = 180355072;
  if (ws_size < WS_NEED) return;

  unsigned short* WqT = (unsigned short*)(ws + OFF_WQT);
  unsigned short* WoT = (unsigned short*)(ws + OFF_WOT);
  unsigned short* WkT = (unsigned short*)(ws + OFF_WKT);
  unsigned short* WvT = (unsigned short*)(ws + OFF_WVT);
  unsigned short* qb = (unsigned short*)(ws + OFF_QB);
  unsigned short* kb = (unsigned short*)(ws + OFF_KB);
  unsigned short* vb = (unsigned short*)(ws + OFF_VB);
  unsigned short* Qp = (unsigned short*)(ws + OFF_QP);
  unsigned short* Kp = (unsigned short*)(ws + OFF_KP);
  unsigned short* Vp = (unsigned short*)(ws + OFF_VP);
  unsigned short* VTb = (unsigned short*)(ws + OFF_VT);
  unsigned short* attnb = (unsigned short*)(ws + OFF_AT);
  float2* tab = (float2*)(ws + OFF_QB);  // reuses qb region (dead after GEMMs)

  transpose_cast_kernel<<<dim3(64, 64), 256, 0, stream>>>(Wq, WqT, DM, NQH * HD);
  transpose_cast_kernel<<<dim3(64, 16), 256, 0, stream>>>(Wk, WkT, DM, NKVH * HD);
  transpose_cast_kernel<<<dim3(64, 16), 256, 0, stream>>>(Wv, WvT, DM, NKVH * HD);
  transpose_cast_kernel<<<dim3(64, 64), 256, 0, stream>>>(Wo, WoT, NQH * HD, DM);
  cast3_kernel<<<dim3(4096, 1, 3), 256, 0, stream>>>(query, key, value, qb, kb, vb);
  gemm_bt_kernel<false, false><<<dim3(32, 16, 1), 256, 0, stream>>>(
      qb, WqT, Qp, nullptr, nullptr, nullptr, T_SEQ, NQH * HD, DM);
  gemm_bt_kernel<false, true><<<dim3(8, 16, 2), 256, 0, stream>>>(
      kb, WkT, Kp, vb, WvT, Vp, T_SEQ, NKVH * HD, DM);
  // table overwrites qb region -- only after projection GEMMs are enqueued
  sincos_kernel<<<dim3(T_SEQ * 64 / 256), 256, 0, stream>>>(tab);
  constexpr float C1 = (float)(0.08838834764831845 * 1.4426950408889634 / 15.0);
  rope_kernel<<<dim3(T_SEQ * NQH * 64 / 256), 256, 0, stream>>>(Qp, tab, 5, C1);
  rope_kernel<<<dim3(T_SEQ * NKVH * 64 / 256), 256, 0, stream>>>(Kp, tab, 3, 1.0f);
  vtrans_kernel<<<dim3(NKVH * HD * T_SEQ / (256 * 8)), 256, 0, stream>>>(Vp, VTb);
  attn_kernel<<<dim3(16, 16), 512, 0, stream>>>(Qp, Kp, VTb, attnb);
  gemm_bt_kernel<true, false><<<dim3(32, 16, 1), 256, 0, stream>>>(
      attnb, WoT, out, nullptr, nullptr, nullptr, T_SEQ, DM, DM);
}

// Round 4
// 433.299 us; speedup vs baseline: 1.5414x; 1.1455x over previous
//
#include <hip/hip_runtime.h>
#include <hip/hip_bf16.h>
#include <stdint.h>
#include <stddef.h>

// Problem constants
#define T_SEQ 2048
#define DM    4096
#define NQH   32
#define NKVH  8
#define HD    128
#define ATTN_MULT 0.08838834764831845f

typedef __attribute__((ext_vector_type(8))) short bf16x8;
typedef __attribute__((ext_vector_type(4))) float f32x4;
typedef __attribute__((ext_vector_type(4))) unsigned int u32x4;

__device__ __forceinline__ unsigned short f2b(float f) {
  unsigned u = __builtin_bit_cast(unsigned, f);
  u = u + 0x7FFFu + ((u >> 16) & 1u);
  return (unsigned short)(u >> 16);
}
__device__ __forceinline__ float b2f(unsigned short h) {
  unsigned u = ((unsigned)h) << 16;
  return __builtin_bit_cast(float, u);
}

typedef const __attribute__((address_space(1))) void* gptr1_t;
typedef __attribute__((address_space(3))) void* lptr3_t;
__device__ __forceinline__ void gl_lds16(const void* g, void* l) {
  __builtin_amdgcn_global_load_lds((gptr1_t)g, (lptr3_t)l, 16, 0, 0);
}

// ---------------------------------------------------------------------------
// Transpose + cast: W (K,N) f32 -> WT (N,K) bf16
// ---------------------------------------------------------------------------
__global__ __launch_bounds__(256) void transpose_cast_kernel(
    const float* __restrict__ W, unsigned short* __restrict__ WT, int K, int N) {
  __shared__ float tile[64][65];
  int k0 = blockIdx.x * 64;
  int n0 = blockIdx.y * 64;
  int t = threadIdx.x;
  int rr = t >> 4;
  int cc = t & 15;
#pragma unroll
  for (int c = 0; c < 4; ++c) {
    int row = c * 16 + rr;
    float4 v = *(const float4*)&W[(size_t)(k0 + row) * N + n0 + cc * 4];
    tile[row][cc * 4 + 0] = v.x;
    tile[row][cc * 4 + 1] = v.y;
    tile[row][cc * 4 + 2] = v.z;
    tile[row][cc * 4 + 3] = v.w;
  }
  __syncthreads();
  int orow = t >> 2;
  int kb = (t & 3) * 16;
  u32x4 o1, o2;
#pragma unroll
  for (int u = 0; u < 4; ++u) {
    o1[u] = (unsigned)f2b(tile[kb + 2 * u][orow]) |
            ((unsigned)f2b(tile[kb + 2 * u + 1][orow]) << 16);
    o2[u] = (unsigned)f2b(tile[kb + 8 + 2 * u][orow]) |
            ((unsigned)f2b(tile[kb + 9 + 2 * u][orow]) << 16);
  }
  unsigned short* dst = &WT[(size_t)(n0 + orow) * K + k0 + kb];
  *(u32x4*)dst = o1;
  *(u32x4*)(dst + 8) = o2;
}

// ---------------------------------------------------------------------------
// Cast 3 activation tensors f32 -> bf16
// ---------------------------------------------------------------------------
__global__ __launch_bounds__(256) void cast3_kernel(
    const float* __restrict__ a0, const float* __restrict__ a1, const float* __restrict__ a2,
    unsigned short* __restrict__ b0, unsigned short* __restrict__ b1, unsigned short* __restrict__ b2) {
  const float* in = blockIdx.z == 0 ? a0 : (blockIdx.z == 1 ? a1 : a2);
  unsigned short* out = blockIdx.z == 0 ? b0 : (blockIdx.z == 1 ? b1 : b2);
  size_t idx = ((size_t)blockIdx.x * 256 + threadIdx.x) * 8;
  float4 x = *(const float4*)(in + idx);
  float4 y = *(const float4*)(in + idx + 4);
  u32x4 v;
  v[0] = (unsigned)f2b(x.x) | ((unsigned)f2b(x.y) << 16);
  v[1] = (unsigned)f2b(x.z) | ((unsigned)f2b(x.w) << 16);
  v[2] = (unsigned)f2b(y.x) | ((unsigned)f2b(y.y) << 16);
  v[3] = (unsigned)f2b(y.z) | ((unsigned)f2b(y.w) << 16);
  *(u32x4*)(out + idx) = v;
}

// ---------------------------------------------------------------------------
// Deep-pipelined GEMM: C(M,N) = A(M,K) * BT(N,K)^T, bf16 in, fp32 accum.
// BM=128 BN=256 BK=64, 8 waves (2Mx4N, 64x64/wave), 3-buffer LDS (144KB),
// counted vmcnt(6) (never 0 in main loop), swizzled LDS (T2), setprio (T5).
// Requires N%256==0, M%128==0, K%64==0, K/64>=3, gridDim.x = N/256 (%8==0... 
// here N=4096 -> 16), gridDim.y = M/128.
// ---------------------------------------------------------------------------
template <bool F32OUT>
__global__ __launch_bounds__(512, 1) void gemm_dp_kernel(
    const unsigned short* __restrict__ A, const unsigned short* __restrict__ BT,
    void* __restrict__ C, int M, int N, int K) {
  __shared__ unsigned short lds[3 * 24576];  // 3 x (A 16KB + B 32KB)

  // XCD mapping: all m-blocks of an n-panel on one XCD (B-panel fits 4MB L2)
  int nx = gridDim.x;                 // n-tiles (16)
  int flat = blockIdx.y * nx + blockIdx.x;
  int npx = nx >> 3;                  // n-tiles per XCD
  int xcd = flat & 7, idx = flat >> 3;
  int n0 = (xcd * npx + idx % npx) * 256;
  int m0 = (idx / npx) * 128;

  int t = threadIdx.x;
  int w = t >> 6, l = t & 63;
  int wm = w >> 2, wn = w & 3;        // 2M x 4N wave grid
  int lr = l & 15, lh = l >> 4;

  f32x4 acc[4][4] = {};

  int lrow8 = l >> 3;                         // row within 8-row chunk
  int scb = ((l & 7) ^ lrow8) << 4;           // pre-swizzled source col-byte
  const int NT = K >> 6;

  auto stage = [&](int tt, int bsel) {
    int kb = tt * 64;
#pragma unroll
    for (int c = 0; c < 6; ++c) {
      int chunk = w * 6 + c;                  // 0..15 A, 16..47 B
      if (chunk < 16) {
        const char* src = (const char*)A +
            ((size_t)(m0 + chunk * 8 + lrow8) * K + kb) * 2 + scb;
        gl_lds16(src, (char*)lds + bsel * 49152 + chunk * 1024);
      } else {
        const char* src = (const char*)BT +
            ((size_t)(n0 + (chunk - 16) * 8 + lrow8) * K + kb) * 2 + scb;
        gl_lds16(src, (char*)lds + bsel * 49152 + 16384 + (chunk - 16) * 1024);
      }
    }
  };

  stage(0, 0);
  stage(1, 1);
  asm volatile("s_waitcnt vmcnt(6)" ::: "memory");  // tile0 landed, tile1 in flight
  __builtin_amdgcn_s_barrier();

  int bsel = 0, bnext = 2;
  for (int tt = 0; tt < NT; ++tt) {
    bool pre = (tt + 2 < NT);
    if (pre) stage(tt + 2, bnext);            // buffer freed at end of tile t-1
    const char* Ab = (const char*)lds + bsel * 49152;
    const char* Bb = Ab + 16384;
#pragma unroll
    for (int ks = 0; ks < 2; ++ks) {
      bf16x8 af[4], bfp[4];
      int cswz = ks * 64;                     // (ks*32 cols)*2B
#pragma unroll
      for (int i = 0; i < 4; ++i) {
        int row = wm * 64 + i * 16 + lr;
        af[i] = *(const bf16x8*)(Ab + row * 128 + ((cswz + lh * 16) ^ ((lr & 7) << 4)));
      }
#pragma unroll
      for (int j = 0; j < 4; ++j) {
        int row = wn * 64 + j * 16 + lr;
        bfp[j] = *(const bf16x8*)(Bb + row * 128 + ((cswz + lh * 16) ^ ((lr & 7) << 4)));
      }
      __builtin_amdgcn_s_setprio(1);
#pragma unroll
      for (int i = 0; i < 4; ++i)
#pragma unroll
        for (int j = 0; j < 4; ++j)
          acc[i][j] = __builtin_amdgcn_mfma_f32_16x16x32_bf16(af[i], bfp[j], acc[i][j], 0, 0, 0);
      __builtin_amdgcn_s_setprio(0);
    }
    if (pre) asm volatile("s_waitcnt vmcnt(6)" ::: "memory");  // next tile landed
    else     asm volatile("s_waitcnt vmcnt(0)" ::: "memory");  // epilogue drain
    __builtin_amdgcn_s_barrier();
    bsel = (bsel == 2) ? 0 : bsel + 1;
    bnext = (bnext == 2) ? 0 : bnext + 1;
  }

#pragma unroll
  for (int i = 0; i < 4; ++i) {
#pragma unroll
    for (int j = 0; j < 4; ++j) {
#pragma unroll
      for (int r = 0; r < 4; ++r) {
        int row = m0 + wm * 64 + i * 16 + lh * 4 + r;
        int col = n0 + wn * 64 + j * 16 + lr;
        if constexpr (F32OUT)
          ((float*)C)[(size_t)row * N + col] = acc[i][j][r];
        else
          ((unsigned short*)C)[(size_t)row * N + col] = f2b(acc[i][j][r]);
      }
    }
  }
}

// ---------------------------------------------------------------------------
// GEMM (m97 structure) for the small K/V projections, dual via blockIdx.z
// ---------------------------------------------------------------------------
template <bool F32OUT, bool DUAL>
__global__ __launch_bounds__(256) void gemm_bt_kernel(
    const unsigned short* __restrict__ A0, const unsigned short* __restrict__ B0, void* __restrict__ C0,
    const unsigned short* __restrict__ A1, const unsigned short* __restrict__ B1, void* __restrict__ C1,
    int M, int N, int K) {
  __shared__ unsigned short As[128 * 32];
  __shared__ unsigned short Bs[128 * 32];
  const unsigned short* A = A0;
  const unsigned short* BT = B0;
  void* C = C0;
  if (DUAL && blockIdx.z == 1) { A = A1; BT = B1; C = C1; }

  int nx = gridDim.x;
  int flat = blockIdx.y * nx + blockIdx.x;
  int cpx = (nx * gridDim.y) >> 3;
  int swz = (flat & 7) * cpx + (flat >> 3);
  int m0 = (swz / nx) * 128;
  int n0 = (swz % nx) * 128;

  int t = threadIdx.x;
  int w = t >> 6, l = t & 63;
  int wr = w >> 1, wc = w & 1;
  int lr = l & 15, lh = l >> 4;

  f32x4 acc[4][4] = {};

  int srow0 = (w * 2 + 0) * 16 + (l >> 2);
  int srow1 = (w * 2 + 1) * 16 + (l >> 2);
  int scol = (l & 3) * 8;
  const unsigned short* Aa0 = A + (size_t)(m0 + srow0) * K + scol;
  const unsigned short* Aa1 = A + (size_t)(m0 + srow1) * K + scol;
  const unsigned short* Ba0 = BT + (size_t)(n0 + srow0) * K + scol;
  const unsigned short* Ba1 = BT + (size_t)(n0 + srow1) * K + scol;
  unsigned short* Al0 = &As[(w * 2 + 0) * 512];
  unsigned short* Al1 = &As[(w * 2 + 1) * 512];
  unsigned short* Bl0 = &Bs[(w * 2 + 0) * 512];
  unsigned short* Bl1 = &Bs[(w * 2 + 1) * 512];

  for (int k0 = 0; k0 < K; k0 += 32) {
    gl_lds16(Aa0 + k0, Al0);
    gl_lds16(Aa1 + k0, Al1);
    gl_lds16(Ba0 + k0, Bl0);
    gl_lds16(Ba1 + k0, Bl1);
    __syncthreads();
    bf16x8 af[4], bfr[4];
#pragma unroll
    for (int i = 0; i < 4; ++i)
      af[i] = *(const bf16x8*)&As[(wr * 64 + i * 16 + lr) * 32 + lh * 8];
#pragma unroll
    for (int j = 0; j < 4; ++j)
      bfr[j] = *(const bf16x8*)&Bs[(wc * 64 + j * 16 + lr) * 32 + lh * 8];
#pragma unroll
    for (int i = 0; i < 4; ++i)
#pragma unroll
      for (int j = 0; j < 4; ++j)
        acc[i][j] = __builtin_amdgcn_mfma_f32_16x16x32_bf16(af[i], bfr[j], acc[i][j], 0, 0, 0);
    __syncthreads();
  }

#pragma unroll
  for (int i = 0; i < 4; ++i) {
#pragma unroll
    for (int j = 0; j < 4; ++j) {
#pragma unroll
      for (int r = 0; r < 4; ++r) {
        int row = m0 + wr * 64 + i * 16 + lh * 4 + r;
        int col = n0 + wc * 64 + j * 16 + lr;
        if constexpr (F32OUT)
          ((float*)C)[(size_t)row * N + col] = acc[i][j][r];
        else
          ((unsigned short*)C)[(size_t)row * N + col] = f2b(acc[i][j][r]);
      }
    }
  }
}

// ---------------------------------------------------------------------------
// sincos table: tab[t*64+i] = (cos, sin) of pos t, freq i
// ---------------------------------------------------------------------------
__global__ __launch_bounds__(256) void sincos_kernel(float2* __restrict__ tab) {
  int idx = blockIdx.x * 256 + threadIdx.x;
  int i = idx & 63;
  int tpos = idx >> 6;
  float invf = exp2f(-(float)i * (13.287712379549449f / 64.0f));
  float phase = (float)tpos * invf;
  float s, c;
  sincosf(phase, &s, &c);
  tab[idx] = make_float2(c, s);
}

// ---------------------------------------------------------------------------
// RoPE in place on (T, nheads*128) bf16, with output scale (C1 folded into Q)
// ---------------------------------------------------------------------------
__global__ __launch_bounds__(256) void rope_kernel(unsigned short* __restrict__ X,
                                                   const float2* __restrict__ tab,
                                                   int hshift, float scale) {
  int idx = blockIdx.x * 256 + threadIdx.x;
  int i = idx & 63;
  int rest = idx >> 6;
  int nheads = 1 << hshift;
  int hh = rest & (nheads - 1);
  int tpos = rest >> hshift;
  float2 cs = tab[tpos * 64 + i];
  size_t base = (size_t)tpos * ((size_t)nheads * HD) + (size_t)hh * HD + i;
  float x1 = b2f(X[base]);
  float x2 = b2f(X[base + 64]);
  X[base] = f2b((x1 * cs.x - x2 * cs.y) * scale);
  X[base + 64] = f2b((x2 * cs.x + x1 * cs.y) * scale);
}

// ---------------------------------------------------------------------------
// V (T, NKVH*HD) bf16 -> VT (NKVH, HD, T) bf16
// ---------------------------------------------------------------------------
__global__ __launch_bounds__(256) void vtrans_kernel(
    const unsigned short* __restrict__ V, unsigned short* __restrict__ VT) {
  size_t flat = ((size_t)blockIdx.x * 256 + threadIdx.x) * 8;
  int t8 = (int)(flat & (T_SEQ - 1));
  int dh = (int)(flat >> 11);
  u32x4 v;
#pragma unroll
  for (int u = 0; u < 4; ++u) {
    unsigned short lo = V[(size_t)(t8 + 2 * u) * (NKVH * HD) + dh];
    unsigned short hi = V[(size_t)(t8 + 2 * u + 1) * (NKVH * HD) + dh];
    v[u] = (unsigned)lo | ((unsigned)hi << 16);
  }
  *(u32x4*)(VT + flat) = v;
}

// ---------------------------------------------------------------------------
// Attention v3 helpers (unchanged from round 3)
// ---------------------------------------------------------------------------
template <bool DIAG>
__device__ __forceinline__ void softmax_frag(const f32x4 s[4], float& lsum, bf16x8 pf[2],
                                             int lr, int lh, int wq) {
  constexpr float C2f = (float)(-60.0 * 1.4426950408889634);
  float pv[4][4];
#pragma unroll
  for (int ct = 0; ct < 4; ++ct)
#pragma unroll
    for (int r = 0; r < 4; ++r) {
      float u = exp2f(s[ct][r]);
      float p = exp2f(C2f * __builtin_amdgcn_rcpf(u + 1.0f));
      if constexpr (DIAG) {
        int kg = ct * 16 + lh * 4 + r;
        int qg = wq * 16 + lr;
        if (kg > qg) p = 0.0f;
      }
      pv[ct][r] = p;
      lsum += p;
    }
  unsigned pk[4][2];
#pragma unroll
  for (int ct = 0; ct < 4; ++ct) {
    pk[ct][0] = (unsigned)f2b(pv[ct][0]) | ((unsigned)f2b(pv[ct][1]) << 16);
    pk[ct][1] = (unsigned)f2b(pv[ct][2]) | ((unsigned)f2b(pv[ct][3]) << 16);
  }
  int s0 = ((lh & 1) << 5) + lr;
  int s1 = s0 + 16;
  bool hi = (lh >= 2);
#pragma unroll
  for (int ks = 0; ks < 2; ++ks) {
    unsigned a0 = (unsigned)__shfl((int)pk[2 * ks][0], s0, 64);
    unsigned a1 = (unsigned)__shfl((int)pk[2 * ks][1], s0, 64);
    unsigned a2 = (unsigned)__shfl((int)pk[2 * ks][0], s1, 64);
    unsigned a3 = (unsigned)__shfl((int)pk[2 * ks][1], s1, 64);
    unsigned b0 = (unsigned)__shfl((int)pk[2 * ks + 1][0], s0, 64);
    unsigned b1 = (unsigned)__shfl((int)pk[2 * ks + 1][1], s0, 64);
    unsigned b2 = (unsigned)__shfl((int)pk[2 * ks + 1][0], s1, 64);
    unsigned b3 = (unsigned)__shfl((int)pk[2 * ks + 1][1], s1, 64);
    u32x4 f;
    f[0] = hi ? b0 : a0;
    f[1] = hi ? b1 : a1;
    f[2] = hi ? b2 : a2;
    f[3] = hi ? b3 : a3;
    pf[ks] = __builtin_bit_cast(bf16x8, f);
  }
}

template <bool WITHA, bool DIAGA, bool DIAGB>
__device__ __forceinline__ void attn_tile(
    const char* KsCur, const char* VsCur,
    const bf16x8 qfA[4], const bf16x8 qfB[4],
    f32x4 oaccA[8], f32x4 oaccB[8],
    float& lsumA, float& lsumB,
    int lr, int lh, int wq) {
  f32x4 sB[4], sA[4];
#pragma unroll
  for (int ct = 0; ct < 4; ++ct) {
    f32x4 zB = {};
    f32x4 zA = {};
#pragma unroll
    for (int kk = 0; kk < 4; ++kk) {
      int row = ct * 16 + lr;
      int cb = (kk * 32 + lh * 8) * 2;
      bf16x8 kf = *(const bf16x8*)(KsCur + row * 256 + (cb ^ ((row & 7) << 4)));
      zB = __builtin_amdgcn_mfma_f32_16x16x32_bf16(kf, qfB[kk], zB, 0, 0, 0);
      if constexpr (WITHA) zA = __builtin_amdgcn_mfma_f32_16x16x32_bf16(kf, qfA[kk], zA, 0, 0, 0);
    }
    sB[ct] = zB;
    if constexpr (WITHA) sA[ct] = zA;
  }
  bf16x8 pfB[2], pfA[2];
  softmax_frag<DIAGB>(sB, lsumB, pfB, lr, lh, wq);
  if constexpr (WITHA) softmax_frag<DIAGA>(sA, lsumA, pfA, lr, lh, wq);
#pragma unroll
  for (int ks = 0; ks < 2; ++ks) {
    int pcb = (ks * 32 + lh * 8) * 2;
#pragma unroll
    for (int dt = 0; dt < 8; ++dt) {
      int vrow = dt * 16 + lr;
      bf16x8 vf = *(const bf16x8*)(VsCur + ((vrow * 128 + pcb) ^ ((vrow & 7) << 4)));
      oaccB[dt] = __builtin_amdgcn_mfma_f32_16x16x32_bf16(pfB[ks], vf, oaccB[dt], 0, 0, 0);
      if constexpr (WITHA) oaccA[dt] = __builtin_amdgcn_mfma_f32_16x16x32_bf16(pfA[ks], vf, oaccA[dt], 0, 0, 0);
    }
  }
}

// ---------------------------------------------------------------------------
// Flash attention v3 (round 3, unchanged): folded q-tile pairs, 2 heads/block,
// 8 waves, KV tiles of 64 double-buffered, P in registers. 64KB LDS.
// ---------------------------------------------------------------------------
__global__ __launch_bounds__(512, 2) void attn_kernel(
    const unsigned short* __restrict__ Q,
    const unsigned short* __restrict__ Kx,
    const unsigned short* __restrict__ VT,
    unsigned short* __restrict__ O) {
  __shared__ unsigned short Ks[2][64 * 128];
  __shared__ unsigned short Vs[2][128 * 64];

  int bx = blockIdx.x;
  int by = blockIdx.y;
  int qtA = bx, qtB = 31 - bx;
  int t = threadIdx.x;
  int w = t >> 6, l = t & 63;
  int wq = w & 3;
  int hh = by * 2 + (w >> 2);
  int kvh = by >> 1;
  int lr = l & 15, lh = l >> 4;

  bf16x8 qfA[4], qfB[4];
  {
    const unsigned short* qpA = Q + (size_t)(qtA * 64 + wq * 16 + lr) * (NQH * HD) + hh * HD + lh * 8;
    const unsigned short* qpB = Q + (size_t)(qtB * 64 + wq * 16 + lr) * (NQH * HD) + hh * HD + lh * 8;
#pragma unroll
    for (int kk = 0; kk < 4; ++kk) {
      qfA[kk] = *(const bf16x8*)(qpA + kk * 32);
      qfB[kk] = *(const bf16x8*)(qpB + kk * 32);
    }
  }

  f32x4 oaccA[8] = {}, oaccB[8] = {};
  float lsumA = 0.f, lsumB = 0.f;

  const char* KgB = (const char*)Kx + (size_t)kvh * HD * 2;
  const char* VgB = (const char*)VT + (size_t)kvh * HD * T_SEQ * 2;

  auto stage = [&](int kt, int b) {
#pragma unroll
    for (int c = 0; c < 2; ++c) {
      int chunk = w * 2 + c;
      int p = chunk * 1024 + l * 16;
      {
        int row = p >> 8;
        int cb = p & 255;
        int cbl = cb ^ ((row & 7) << 4);
        gl_lds16(KgB + (size_t)(kt * 64 + row) * (NKVH * HD * 2) + cbl,
                 (char*)Ks[b] + chunk * 1024);
      }
      {
        int row = p >> 7;
        int cb = p & 127;
        int cbl = cb ^ ((row & 7) << 4);
        gl_lds16(VgB + (size_t)row * (T_SEQ * 2) + (size_t)kt * 128 + cbl,
                 (char*)Vs[b] + chunk * 1024);
      }
    }
  };

  stage(0, 0);
  __syncthreads();

  int cur = 0;
  for (int kt = 0; kt <= qtB; ++kt) {
    if (kt < qtB) stage(kt + 1, cur ^ 1);
    const char* Kc = (const char*)Ks[cur];
    const char* Vc = (const char*)Vs[cur];
    if (kt < qtA)
      attn_tile<true, false, false>(Kc, Vc, qfA, qfB, oaccA, oaccB, lsumA, lsumB, lr, lh, wq);
    else if (kt == qtA)
      attn_tile<true, true, false>(Kc, Vc, qfA, qfB, oaccA, oaccB, lsumA, lsumB, lr, lh, wq);
    else if (kt < qtB)
      attn_tile<false, false, false>(Kc, Vc, qfA, qfB, oaccA, oaccB, lsumA, lsumB, lr, lh, wq);
    else
      attn_tile<false, false, true>(Kc, Vc, qfA, qfB, oaccA, oaccB, lsumA, lsumB, lr, lh, wq);
    __syncthreads();
    cur ^= 1;
  }

  lsumB += __shfl_xor(lsumB, 16, 64);
  lsumB += __shfl_xor(lsumB, 32, 64);
  lsumA += __shfl_xor(lsumA, 16, 64);
  lsumA += __shfl_xor(lsumA, 32, 64);

#pragma unroll
  for (int i = 0; i < 4; ++i) {
    int srcl = (l & 48) | (lh * 4 + i);
    float invB = 1.0f / __shfl(lsumB, srcl, 64);
    float invA = 1.0f / __shfl(lsumA, srcl, 64);
    int qgB = qtB * 64 + wq * 16 + lh * 4 + i;
    int qgA = qtA * 64 + wq * 16 + lh * 4 + i;
#pragma unroll
    for (int dt = 0; dt < 8; ++dt) {
      O[(size_t)qgB * (NQH * HD) + hh * HD + dt * 16 + lr] = f2b(oaccB[dt][i] * invB);
      O[(size_t)qgA * (NQH * HD) + hh * HD + dt * 16 + lr] = f2b(oaccA[dt][i] * invA);
    }
  }
}

// ---------------------------------------------------------------------------
extern "C" void kernel_launch(void* const* d_in, const int* in_sizes, int n_in,
                              void* d_out, int out_size, void* d_ws, size_t ws_size,
                              hipStream_t stream) {
  const float* query = (const float*)d_in[0];
  const float* key = (const float*)d_in[1];
  const float* value = (const float*)d_in[2];
  // d_in[3] = mask (tril causal) -- hardcoded
  const float* Wq = (const float*)d_in[4];
  const float* Wk = (const float*)d_in[5];
  const float* Wv = (const float*)d_in[6];
  const float* Wo = (const float*)d_in[7];
  float* out = (float*)d_out;

  char* ws = (char*)d_ws;
  constexpr size_t OFF_WQT = 0;
  constexpr size_t OFF_WOT = 33554432;
  constexpr size_t OFF_WKT = 67108864;
  constexpr size_t OFF_WVT = 75497472;
  constexpr size_t OFF_QB = 83886080;
  constexpr size_t OFF_KB = 100663296;
  constexpr size_t OFF_VB = 117440512;
  constexpr size_t OFF_QP = 134217728;
  constexpr size_t OFF_KP = 150994944;
  constexpr size_t OFF_VP = 155189248;
  constexpr size_t OFF_VT = 159383552;
  constexpr size_t OFF_AT = 163577856;
  constexpr size_t WS_NEED = 180355072;
  if (ws_size < WS_NEED) return;

  unsigned short* WqT = (unsigned short*)(ws + OFF_WQT);
  unsigned short* WoT = (unsigned short*)(ws + OFF_WOT);
  unsigned short* WkT = (unsigned short*)(ws + OFF_WKT);
  unsigned short* WvT = (unsigned short*)(ws + OFF_WVT);
  unsigned short* qb = (unsigned short*)(ws + OFF_QB);
  unsigned short* kb = (unsigned short*)(ws + OFF_KB);
  unsigned short* vb = (unsigned short*)(ws + OFF_VB);
  unsigned short* Qp = (unsigned short*)(ws + OFF_QP);
  unsigned short* Kp = (unsigned short*)(ws + OFF_KP);
  unsigned short* Vp = (unsigned short*)(ws + OFF_VP);
  unsigned short* VTb = (unsigned short*)(ws + OFF_VT);
  unsigned short* attnb = (unsigned short*)(ws + OFF_AT);
  float2* tab = (float2*)(ws + OFF_QB);  // reuses qb region (dead after Q GEMM)

  transpose_cast_kernel<<<dim3(64, 64), 256, 0, stream>>>(Wq, WqT, DM, NQH * HD);
  transpose_cast_kernel<<<dim3(64, 16), 256, 0, stream>>>(Wk, WkT, DM, NKVH * HD);
  transpose_cast_kernel<<<dim3(64, 16), 256, 0, stream>>>(Wv, WvT, DM, NKVH * HD);
  transpose_cast_kernel<<<dim3(64, 64), 256, 0, stream>>>(Wo, WoT, NQH * HD, DM);
  cast3_kernel<<<dim3(4096, 1, 3), 256, 0, stream>>>(query, key, value, qb, kb, vb);
  // Q projection: deep-pipelined GEMM (M=2048, N=4096, K=4096)
  gemm_dp_kernel<false><<<dim3(16, 16), 512, 0, stream>>>(
      qb, WqT, Qp, T_SEQ, NQH * HD, DM);
  // K,V projections (N=1024): m97 dual kernel
  gemm_bt_kernel<false, true><<<dim3(8, 16, 2), 256, 0, stream>>>(
      kb, WkT, Kp, vb, WvT, Vp, T_SEQ, NKVH * HD, DM);
  sincos_kernel<<<dim3(T_SEQ * 64 / 256), 256, 0, stream>>>(tab);
  constexpr float C1 = (float)(0.08838834764831845 * 1.4426950408889634 / 15.0);
  rope_kernel<<<dim3(T_SEQ * NQH * 64 / 256), 256, 0, stream>>>(Qp, tab, 5, C1);
  rope_kernel<<<dim3(T_SEQ * NKVH * 64 / 256), 256, 0, stream>>>(Kp, tab, 3, 1.0f);
  vtrans_kernel<<<dim3(NKVH * HD * T_SEQ / (256 * 8)), 256, 0, stream>>>(Vp, VTb);
  attn_kernel<<<dim3(16, 16), 512, 0, stream>>>(Qp, Kp, VTb, attnb);
  // Output projection: deep-pipelined GEMM (M=2048, N=4096, K=4096), f32 out
  gemm_dp_kernel<true><<<dim3(16, 16), 512, 0, stream>>>(
      attnb, WoT, out, T_SEQ, DM, DM);
}

// Round 5
// 400.879 us; speedup vs baseline: 1.6661x; 1.0809x over previous
//
#include <hip/hip_runtime.h>
#include <hip/hip_bf16.h>
#include <stdint.h>
#include <stddef.h>

// Problem constants
#define T_SEQ 2048
#define DM    4096
#define NQH   32
#define NKVH  8
#define HD    128
#define ATTN_MULT 0.08838834764831845f

typedef __attribute__((ext_vector_type(8))) short bf16x8;
typedef __attribute__((ext_vector_type(4))) float f32x4;
typedef __attribute__((ext_vector_type(4))) unsigned int u32x4;

__device__ __forceinline__ unsigned short f2b(float f) {
  unsigned u = __builtin_bit_cast(unsigned, f);
  u = u + 0x7FFFu + ((u >> 16) & 1u);
  return (unsigned short)(u >> 16);
}
__device__ __forceinline__ float b2f(unsigned short h) {
  unsigned u = ((unsigned)h) << 16;
  return __builtin_bit_cast(float, u);
}

typedef const __attribute__((address_space(1))) void* gptr1_t;
typedef __attribute__((address_space(3))) void* lptr3_t;
__device__ __forceinline__ void gl_lds16(const void* g, void* l) {
  __builtin_amdgcn_global_load_lds((gptr1_t)g, (lptr3_t)l, 16, 0, 0);
}

// ---------------------------------------------------------------------------
// Transpose + cast: W (K,N) f32 -> WT (N,K) bf16
// ---------------------------------------------------------------------------
__global__ __launch_bounds__(256) void transpose_cast_kernel(
    const float* __restrict__ W, unsigned short* __restrict__ WT, int K, int N) {
  __shared__ float tile[64][65];
  int k0 = blockIdx.x * 64;
  int n0 = blockIdx.y * 64;
  int t = threadIdx.x;
  int rr = t >> 4;
  int cc = t & 15;
#pragma unroll
  for (int c = 0; c < 4; ++c) {
    int row = c * 16 + rr;
    float4 v = *(const float4*)&W[(size_t)(k0 + row) * N + n0 + cc * 4];
    tile[row][cc * 4 + 0] = v.x;
    tile[row][cc * 4 + 1] = v.y;
    tile[row][cc * 4 + 2] = v.z;
    tile[row][cc * 4 + 3] = v.w;
  }
  __syncthreads();
  int orow = t >> 2;
  int kb = (t & 3) * 16;
  u32x4 o1, o2;
#pragma unroll
  for (int u = 0; u < 4; ++u) {
    o1[u] = (unsigned)f2b(tile[kb + 2 * u][orow]) |
            ((unsigned)f2b(tile[kb + 2 * u + 1][orow]) << 16);
    o2[u] = (unsigned)f2b(tile[kb + 8 + 2 * u][orow]) |
            ((unsigned)f2b(tile[kb + 9 + 2 * u][orow]) << 16);
  }
  unsigned short* dst = &WT[(size_t)(n0 + orow) * K + k0 + kb];
  *(u32x4*)dst = o1;
  *(u32x4*)(dst + 8) = o2;
}

// ---------------------------------------------------------------------------
// Cast 3 activation tensors f32 -> bf16
// ---------------------------------------------------------------------------
__global__ __launch_bounds__(256) void cast3_kernel(
    const float* __restrict__ a0, const float* __restrict__ a1, const float* __restrict__ a2,
    unsigned short* __restrict__ b0, unsigned short* __restrict__ b1, unsigned short* __restrict__ b2) {
  const float* in = blockIdx.z == 0 ? a0 : (blockIdx.z == 1 ? a1 : a2);
  unsigned short* out = blockIdx.z == 0 ? b0 : (blockIdx.z == 1 ? b1 : b2);
  size_t idx = ((size_t)blockIdx.x * 256 + threadIdx.x) * 8;
  float4 x = *(const float4*)(in + idx);
  float4 y = *(const float4*)(in + idx + 4);
  u32x4 v;
  v[0] = (unsigned)f2b(x.x) | ((unsigned)f2b(x.y) << 16);
  v[1] = (unsigned)f2b(x.z) | ((unsigned)f2b(x.w) << 16);
  v[2] = (unsigned)f2b(y.x) | ((unsigned)f2b(y.y) << 16);
  v[3] = (unsigned)f2b(y.z) | ((unsigned)f2b(y.w) << 16);
  *(u32x4*)(out + idx) = v;
}

// ---------------------------------------------------------------------------
// Deep-pipelined GEMM body: C(M,N) = A(M,K) * BT(N,K)^T, bf16 in, fp32 accum.
// BM=128 BN=256 BK=64, 8 waves (2Mx4N, 64x64/wave), 3-buffer LDS (144KB),
// counted vmcnt(6) (never 0 in main loop), swizzled LDS (T2), setprio (T5).
// Requires N%256==0, M%128==0, K%64==0, K/64>=3.
// ---------------------------------------------------------------------------
template <bool F32OUT>
__device__ __forceinline__ void gemm_dp_body(
    unsigned short* lds,
    const unsigned short* __restrict__ A, const unsigned short* __restrict__ BT,
    void* __restrict__ C, int N, int K, int m0, int n0) {
  int t = threadIdx.x;
  int w = t >> 6, l = t & 63;
  int wm = w >> 2, wn = w & 3;        // 2M x 4N wave grid
  int lr = l & 15, lh = l >> 4;

  f32x4 acc[4][4] = {};

  int lrow8 = l >> 3;                 // row within 8-row chunk
  int scb = ((l & 7) ^ lrow8) << 4;   // pre-swizzled source col-byte
  const int NT = K >> 6;

  auto stage = [&](int tt, int bsel) {
    int kb = tt * 64;
#pragma unroll
    for (int c = 0; c < 6; ++c) {
      int chunk = w * 6 + c;          // 0..15 A, 16..47 B
      if (chunk < 16) {
        const char* src = (const char*)A +
            ((size_t)(m0 + chunk * 8 + lrow8) * K + kb) * 2 + scb;
        gl_lds16(src, (char*)lds + bsel * 49152 + chunk * 1024);
      } else {
        const char* src = (const char*)BT +
            ((size_t)(n0 + (chunk - 16) * 8 + lrow8) * K + kb) * 2 + scb;
        gl_lds16(src, (char*)lds + bsel * 49152 + 16384 + (chunk - 16) * 1024);
      }
    }
  };

  stage(0, 0);
  stage(1, 1);
  asm volatile("s_waitcnt vmcnt(6)" ::: "memory");
  __builtin_amdgcn_s_barrier();

  int bsel = 0, bnext = 2;
  for (int tt = 0; tt < NT; ++tt) {
    bool pre = (tt + 2 < NT);
    if (pre) stage(tt + 2, bnext);
    const char* Ab = (const char*)lds + bsel * 49152;
    const char* Bb = Ab + 16384;
#pragma unroll
    for (int ks = 0; ks < 2; ++ks) {
      bf16x8 af[4], bfp[4];
      int cswz = ks * 64;
#pragma unroll
      for (int i = 0; i < 4; ++i) {
        int row = wm * 64 + i * 16 + lr;
        af[i] = *(const bf16x8*)(Ab + row * 128 + ((cswz + lh * 16) ^ ((lr & 7) << 4)));
      }
#pragma unroll
      for (int j = 0; j < 4; ++j) {
        int row = wn * 64 + j * 16 + lr;
        bfp[j] = *(const bf16x8*)(Bb + row * 128 + ((cswz + lh * 16) ^ ((lr & 7) << 4)));
      }
      __builtin_amdgcn_s_setprio(1);
#pragma unroll
      for (int i = 0; i < 4; ++i)
#pragma unroll
        for (int j = 0; j < 4; ++j)
          acc[i][j] = __builtin_amdgcn_mfma_f32_16x16x32_bf16(af[i], bfp[j], acc[i][j], 0, 0, 0);
      __builtin_amdgcn_s_setprio(0);
    }
    if (pre) asm volatile("s_waitcnt vmcnt(6)" ::: "memory");
    else     asm volatile("s_waitcnt vmcnt(0)" ::: "memory");
    __builtin_amdgcn_s_barrier();
    bsel = (bsel == 2) ? 0 : bsel + 1;
    bnext = (bnext == 2) ? 0 : bnext + 1;
  }

#pragma unroll
  for (int i = 0; i < 4; ++i) {
#pragma unroll
    for (int j = 0; j < 4; ++j) {
#pragma unroll
      for (int r = 0; r < 4; ++r) {
        int row = m0 + wm * 64 + i * 16 + lh * 4 + r;
        int col = n0 + wn * 64 + j * 16 + lr;
        if constexpr (F32OUT)
          ((float*)C)[(size_t)row * N + col] = acc[i][j][r];
        else
          ((unsigned short*)C)[(size_t)row * N + col] = f2b(acc[i][j][r]);
      }
    }
  }
}

// ---------------------------------------------------------------------------
// Fused Q/K/V projection: one flattened 384-block dispatch.
//   flat 0..255:   Q  (N=4096, 16 n-tiles x 16 m-tiles, XCD-mapped)
//   flat 256..319: K  (N=1024, 4 n-tiles x 16 m-tiles)
//   flat 320..383: V  (N=1024)
// All M=2048, K=4096, per-block work identical -> 2 balanced rounds on 256 CUs.
// ---------------------------------------------------------------------------
__global__ __launch_bounds__(512, 1) void qkv_dp_kernel(
    const unsigned short* __restrict__ qb, const unsigned short* __restrict__ WqT, unsigned short* __restrict__ Qp,
    const unsigned short* __restrict__ kb, const unsigned short* __restrict__ WkT, unsigned short* __restrict__ Kp,
    const unsigned short* __restrict__ vb, const unsigned short* __restrict__ WvT, unsigned short* __restrict__ Vp) {
  __shared__ unsigned short lds[3 * 24576];
  int flat = blockIdx.x;
  const unsigned short *A, *BT;
  unsigned short* C;
  int N, m0, n0;
  if (flat < 256) {
    A = qb; BT = WqT; C = Qp; N = NQH * HD;
    int xcd = flat & 7, idx = flat >> 3;   // npx = 2 n-tiles per XCD
    n0 = (xcd * 2 + (idx & 1)) * 256;
    m0 = (idx >> 1) * 128;
  } else {
    int lf = flat - 256;
    int sel = lf >> 6;                     // 0: K, 1: V
    int local = lf & 63;
    A = sel ? vb : kb;
    BT = sel ? WvT : WkT;
    C = sel ? Vp : Kp;
    N = NKVH * HD;
    m0 = (local >> 2) * 128;
    n0 = (local & 3) * 256;
  }
  gemm_dp_body<false>(lds, A, BT, C, N, DM, m0, n0);
}

// ---------------------------------------------------------------------------
// Output projection: deep-pipelined GEMM, f32 out. grid (N/256, M/128).
// ---------------------------------------------------------------------------
__global__ __launch_bounds__(512, 1) void gemm_dp_kernel(
    const unsigned short* __restrict__ A, const unsigned short* __restrict__ BT,
    float* __restrict__ C, int M, int N, int K) {
  __shared__ unsigned short lds[3 * 24576];
  int nx = gridDim.x;
  int flat = blockIdx.y * nx + blockIdx.x;
  int npx = nx >> 3;
  int xcd = flat & 7, idx = flat >> 3;
  int n0 = (xcd * npx + idx % npx) * 256;
  int m0 = (idx / npx) * 128;
  gemm_dp_body<true>(lds, A, BT, C, N, K, m0, n0);
}

// ---------------------------------------------------------------------------
// sincos table: tab[t*64+i] = (cos, sin) of pos t, freq i
// ---------------------------------------------------------------------------
__global__ __launch_bounds__(256) void sincos_kernel(float2* __restrict__ tab) {
  int idx = blockIdx.x * 256 + threadIdx.x;
  int i = idx & 63;
  int tpos = idx >> 6;
  float invf = exp2f(-(float)i * (13.287712379549449f / 64.0f));
  float phase = (float)tpos * invf;
  float s, c;
  sincosf(phase, &s, &c);
  tab[idx] = make_float2(c, s);
}

// ---------------------------------------------------------------------------
// RoPE in place on (T, nheads*128) bf16, with output scale (C1 folded into Q)
// ---------------------------------------------------------------------------
__global__ __launch_bounds__(256) void rope_kernel(unsigned short* __restrict__ X,
                                                   const float2* __restrict__ tab,
                                                   int hshift, float scale) {
  int idx = blockIdx.x * 256 + threadIdx.x;
  int i = idx & 63;
  int rest = idx >> 6;
  int nheads = 1 << hshift;
  int hh = rest & (nheads - 1);
  int tpos = rest >> hshift;
  float2 cs = tab[tpos * 64 + i];
  size_t base = (size_t)tpos * ((size_t)nheads * HD) + (size_t)hh * HD + i;
  float x1 = b2f(X[base]);
  float x2 = b2f(X[base + 64]);
  X[base] = f2b((x1 * cs.x - x2 * cs.y) * scale);
  X[base + 64] = f2b((x2 * cs.x + x1 * cs.y) * scale);
}

// ---------------------------------------------------------------------------
// V (T, NKVH*HD) bf16 -> VT (NKVH, HD, T) bf16
// ---------------------------------------------------------------------------
__global__ __launch_bounds__(256) void vtrans_kernel(
    const unsigned short* __restrict__ V, unsigned short* __restrict__ VT) {
  size_t flat = ((size_t)blockIdx.x * 256 + threadIdx.x) * 8;
  int t8 = (int)(flat & (T_SEQ - 1));
  int dh = (int)(flat >> 11);
  u32x4 v;
#pragma unroll
  for (int u = 0; u < 4; ++u) {
    unsigned short lo = V[(size_t)(t8 + 2 * u) * (NKVH * HD) + dh];
    unsigned short hi = V[(size_t)(t8 + 2 * u + 1) * (NKVH * HD) + dh];
    v[u] = (unsigned)lo | ((unsigned)hi << 16);
  }
  *(u32x4*)(VT + flat) = v;
}

// ---------------------------------------------------------------------------
// Attention v3 helpers (unchanged from round 3)
// ---------------------------------------------------------------------------
template <bool DIAG>
__device__ __forceinline__ void softmax_frag(const f32x4 s[4], float& lsum, bf16x8 pf[2],
                                             int lr, int lh, int wq) {
  constexpr float C2f = (float)(-60.0 * 1.4426950408889634);
  float pv[4][4];
#pragma unroll
  for (int ct = 0; ct < 4; ++ct)
#pragma unroll
    for (int r = 0; r < 4; ++r) {
      float u = exp2f(s[ct][r]);
      float p = exp2f(C2f * __builtin_amdgcn_rcpf(u + 1.0f));
      if constexpr (DIAG) {
        int kg = ct * 16 + lh * 4 + r;
        int qg = wq * 16 + lr;
        if (kg > qg) p = 0.0f;
      }
      pv[ct][r] = p;
      lsum += p;
    }
  unsigned pk[4][2];
#pragma unroll
  for (int ct = 0; ct < 4; ++ct) {
    pk[ct][0] = (unsigned)f2b(pv[ct][0]) | ((unsigned)f2b(pv[ct][1]) << 16);
    pk[ct][1] = (unsigned)f2b(pv[ct][2]) | ((unsigned)f2b(pv[ct][3]) << 16);
  }
  int s0 = ((lh & 1) << 5) + lr;
  int s1 = s0 + 16;
  bool hi = (lh >= 2);
#pragma unroll
  for (int ks = 0; ks < 2; ++ks) {
    unsigned a0 = (unsigned)__shfl((int)pk[2 * ks][0], s0, 64);
    unsigned a1 = (unsigned)__shfl((int)pk[2 * ks][1], s0, 64);
    unsigned a2 = (unsigned)__shfl((int)pk[2 * ks][0], s1, 64);
    unsigned a3 = (unsigned)__shfl((int)pk[2 * ks][1], s1, 64);
    unsigned b0 = (unsigned)__shfl((int)pk[2 * ks + 1][0], s0, 64);
    unsigned b1 = (unsigned)__shfl((int)pk[2 * ks + 1][1], s0, 64);
    unsigned b2 = (unsigned)__shfl((int)pk[2 * ks + 1][0], s1, 64);
    unsigned b3 = (unsigned)__shfl((int)pk[2 * ks + 1][1], s1, 64);
    u32x4 f;
    f[0] = hi ? b0 : a0;
    f[1] = hi ? b1 : a1;
    f[2] = hi ? b2 : a2;
    f[3] = hi ? b3 : a3;
    pf[ks] = __builtin_bit_cast(bf16x8, f);
  }
}

template <bool WITHA, bool DIAGA, bool DIAGB>
__device__ __forceinline__ void attn_tile(
    const char* KsCur, const char* VsCur,
    const bf16x8 qfA[4], const bf16x8 qfB[4],
    f32x4 oaccA[8], f32x4 oaccB[8],
    float& lsumA, float& lsumB,
    int lr, int lh, int wq) {
  f32x4 sB[4], sA[4];
#pragma unroll
  for (int ct = 0; ct < 4; ++ct) {
    f32x4 zB = {};
    f32x4 zA = {};
#pragma unroll
    for (int kk = 0; kk < 4; ++kk) {
      int row = ct * 16 + lr;
      int cb = (kk * 32 + lh * 8) * 2;
      bf16x8 kf = *(const bf16x8*)(KsCur + row * 256 + (cb ^ ((row & 7) << 4)));
      zB = __builtin_amdgcn_mfma_f32_16x16x32_bf16(kf, qfB[kk], zB, 0, 0, 0);
      if constexpr (WITHA) zA = __builtin_amdgcn_mfma_f32_16x16x32_bf16(kf, qfA[kk], zA, 0, 0, 0);
    }
    sB[ct] = zB;
    if constexpr (WITHA) sA[ct] = zA;
  }
  bf16x8 pfB[2], pfA[2];
  softmax_frag<DIAGB>(sB, lsumB, pfB, lr, lh, wq);
  if constexpr (WITHA) softmax_frag<DIAGA>(sA, lsumA, pfA, lr, lh, wq);
#pragma unroll
  for (int ks = 0; ks < 2; ++ks) {
    int pcb = (ks * 32 + lh * 8) * 2;
#pragma unroll
    for (int dt = 0; dt < 8; ++dt) {
      int vrow = dt * 16 + lr;
      bf16x8 vf = *(const bf16x8*)(VsCur + ((vrow * 128 + pcb) ^ ((vrow & 7) << 4)));
      oaccB[dt] = __builtin_amdgcn_mfma_f32_16x16x32_bf16(pfB[ks], vf, oaccB[dt], 0, 0, 0);
      if constexpr (WITHA) oaccA[dt] = __builtin_amdgcn_mfma_f32_16x16x32_bf16(pfA[ks], vf, oaccA[dt], 0, 0, 0);
    }
  }
}

// ---------------------------------------------------------------------------
// Flash attention v3 (unchanged): folded q-tile pairs, 2 heads/block,
// 8 waves, KV tiles of 64 double-buffered, P in registers. 64KB LDS.
// ---------------------------------------------------------------------------
__global__ __launch_bounds__(512, 2) void attn_kernel(
    const unsigned short* __restrict__ Q,
    const unsigned short* __restrict__ Kx,
    const unsigned short* __restrict__ VT,
    unsigned short* __restrict__ O) {
  __shared__ unsigned short Ks[2][64 * 128];
  __shared__ unsigned short Vs[2][128 * 64];

  int bx = blockIdx.x;
  int by = blockIdx.y;
  int qtA = bx, qtB = 31 - bx;
  int t = threadIdx.x;
  int w = t >> 6, l = t & 63;
  int wq = w & 3;
  int hh = by * 2 + (w >> 2);
  int kvh = by >> 1;
  int lr = l & 15, lh = l >> 4;

  bf16x8 qfA[4], qfB[4];
  {
    const unsigned short* qpA = Q + (size_t)(qtA * 64 + wq * 16 + lr) * (NQH * HD) + hh * HD + lh * 8;
    const unsigned short* qpB = Q + (size_t)(qtB * 64 + wq * 16 + lr) * (NQH * HD) + hh * HD + lh * 8;
#pragma unroll
    for (int kk = 0; kk < 4; ++kk) {
      qfA[kk] = *(const bf16x8*)(qpA + kk * 32);
      qfB[kk] = *(const bf16x8*)(qpB + kk * 32);
    }
  }

  f32x4 oaccA[8] = {}, oaccB[8] = {};
  float lsumA = 0.f, lsumB = 0.f;

  const char* KgB = (const char*)Kx + (size_t)kvh * HD * 2;
  const char* VgB = (const char*)VT + (size_t)kvh * HD * T_SEQ * 2;

  auto stage = [&](int kt, int b) {
#pragma unroll
    for (int c = 0; c < 2; ++c) {
      int chunk = w * 2 + c;
      int p = chunk * 1024 + l * 16;
      {
        int row = p >> 8;
        int cb = p & 255;
        int cbl = cb ^ ((row & 7) << 4);
        gl_lds16(KgB + (size_t)(kt * 64 + row) * (NKVH * HD * 2) + cbl,
                 (char*)Ks[b] + chunk * 1024);
      }
      {
        int row = p >> 7;
        int cb = p & 127;
        int cbl = cb ^ ((row & 7) << 4);
        gl_lds16(VgB + (size_t)row * (T_SEQ * 2) + (size_t)kt * 128 + cbl,
                 (char*)Vs[b] + chunk * 1024);
      }
    }
  };

  stage(0, 0);
  __syncthreads();

  int cur = 0;
  for (int kt = 0; kt <= qtB; ++kt) {
    if (kt < qtB) stage(kt + 1, cur ^ 1);
    const char* Kc = (const char*)Ks[cur];
    const char* Vc = (const char*)Vs[cur];
    if (kt < qtA)
      attn_tile<true, false, false>(Kc, Vc, qfA, qfB, oaccA, oaccB, lsumA, lsumB, lr, lh, wq);
    else if (kt == qtA)
      attn_tile<true, true, false>(Kc, Vc, qfA, qfB, oaccA, oaccB, lsumA, lsumB, lr, lh, wq);
    else if (kt < qtB)
      attn_tile<false, false, false>(Kc, Vc, qfA, qfB, oaccA, oaccB, lsumA, lsumB, lr, lh, wq);
    else
      attn_tile<false, false, true>(Kc, Vc, qfA, qfB, oaccA, oaccB, lsumA, lsumB, lr, lh, wq);
    __syncthreads();
    cur ^= 1;
  }

  lsumB += __shfl_xor(lsumB, 16, 64);
  lsumB += __shfl_xor(lsumB, 32, 64);
  lsumA += __shfl_xor(lsumA, 16, 64);
  lsumA += __shfl_xor(lsumA, 32, 64);

#pragma unroll
  for (int i = 0; i < 4; ++i) {
    int srcl = (l & 48) | (lh * 4 + i);
    float invB = 1.0f / __shfl(lsumB, srcl, 64);
    float invA = 1.0f / __shfl(lsumA, srcl, 64);
    int qgB = qtB * 64 + wq * 16 + lh * 4 + i;
    int qgA = qtA * 64 + wq * 16 + lh * 4 + i;
#pragma unroll
    for (int dt = 0; dt < 8; ++dt) {
      O[(size_t)qgB * (NQH * HD) + hh * HD + dt * 16 + lr] = f2b(oaccB[dt][i] * invB);
      O[(size_t)qgA * (NQH * HD) + hh * HD + dt * 16 + lr] = f2b(oaccA[dt][i] * invA);
    }
  }
}

// ---------------------------------------------------------------------------
extern "C" void kernel_launch(void* const* d_in, const int* in_sizes, int n_in,
                              void* d_out, int out_size, void* d_ws, size_t ws_size,
                              hipStream_t stream) {
  const float* query = (const float*)d_in[0];
  const float* key = (const float*)d_in[1];
  const float* value = (const float*)d_in[2];
  // d_in[3] = mask (tril causal) -- hardcoded
  const float* Wq = (const float*)d_in[4];
  const float* Wk = (const float*)d_in[5];
  const float* Wv = (const float*)d_in[6];
  const float* Wo = (const float*)d_in[7];
  float* out = (float*)d_out;

  char* ws = (char*)d_ws;
  constexpr size_t OFF_WQT = 0;
  constexpr size_t OFF_WOT = 33554432;
  constexpr size_t OFF_WKT = 67108864;
  constexpr size_t OFF_WVT = 75497472;
  constexpr size_t OFF_QB = 83886080;
  constexpr size_t OFF_KB = 100663296;
  constexpr size_t OFF_VB = 117440512;
  constexpr size_t OFF_QP = 134217728;
  constexpr size_t OFF_KP = 150994944;
  constexpr size_t OFF_VP = 155189248;
  constexpr size_t OFF_VT = 159383552;
  constexpr size_t OFF_AT = 163577856;
  constexpr size_t WS_NEED = 180355072;
  if (ws_size < WS_NEED) return;

  unsigned short* WqT = (unsigned short*)(ws + OFF_WQT);
  unsigned short* WoT = (unsigned short*)(ws + OFF_WOT);
  unsigned short* WkT = (unsigned short*)(ws + OFF_WKT);
  unsigned short* WvT = (unsigned short*)(ws + OFF_WVT);
  unsigned short* qb = (unsigned short*)(ws + OFF_QB);
  unsigned short* kb = (unsigned short*)(ws + OFF_KB);
  unsigned short* vb = (unsigned short*)(ws + OFF_VB);
  unsigned short* Qp = (unsigned short*)(ws + OFF_QP);
  unsigned short* Kp = (unsigned short*)(ws + OFF_KP);
  unsigned short* Vp = (unsigned short*)(ws + OFF_VP);
  unsigned short* VTb = (unsigned short*)(ws + OFF_VT);
  unsigned short* attnb = (unsigned short*)(ws + OFF_AT);
  float2* tab = (float2*)(ws + OFF_QB);  // reuses qb region (dead after QKV GEMM)

  transpose_cast_kernel<<<dim3(64, 64), 256, 0, stream>>>(Wq, WqT, DM, NQH * HD);
  transpose_cast_kernel<<<dim3(64, 16), 256, 0, stream>>>(Wk, WkT, DM, NKVH * HD);
  transpose_cast_kernel<<<dim3(64, 16), 256, 0, stream>>>(Wv, WvT, DM, NKVH * HD);
  transpose_cast_kernel<<<dim3(64, 64), 256, 0, stream>>>(Wo, WoT, NQH * HD, DM);
  cast3_kernel<<<dim3(4096, 1, 3), 256, 0, stream>>>(query, key, value, qb, kb, vb);
  // Fused Q/K/V projections: 384 flattened dp blocks
  qkv_dp_kernel<<<dim3(384), 512, 0, stream>>>(qb, WqT, Qp, kb, WkT, Kp, vb, WvT, Vp);
  sincos_kernel<<<dim3(T_SEQ * 64 / 256), 256, 0, stream>>>(tab);
  constexpr float C1 = (float)(0.08838834764831845 * 1.4426950408889634 / 15.0);
  rope_kernel<<<dim3(T_SEQ * NQH * 64 / 256), 256, 0, stream>>>(Qp, tab, 5, C1);
  rope_kernel<<<dim3(T_SEQ * NKVH * 64 / 256), 256, 0, stream>>>(Kp, tab, 3, 1.0f);
  vtrans_kernel<<<dim3(NKVH * HD * T_SEQ / (256 * 8)), 256, 0, stream>>>(Vp, VTb);
  attn_kernel<<<dim3(16, 16), 512, 0, stream>>>(Qp, Kp, VTb, attnb);
  // Output projection (M=2048, N=4096, K=4096), f32 out
  gemm_dp_kernel<<<dim3(16, 16), 512, 0, stream>>>(attnb, WoT, out, T_SEQ, DM, DM);
}